// Round 14
// baseline (397.782 us; speedup 1.0000x reference)
//
#include <hip/hip_runtime.h>
#include <hip/hip_bf16.h>
#include <math.h>

#define N_NODES 50000
#define N_EDGES 800000
#define D 64
#define ED 32
#define NB 196   // node blocks = ceil(50000/256)

// ws layout (float-slot offsets). Total ~32.95M slots = 131.8 MB.
#define Q_OFF    0          // bf16 q (1.6M slots)
#define K8_OFF   1600000    // fp8 k: 50k x 64 B = 800k slots
#define V8_OFF   2400000    // fp8 v: 800k slots
#define EE_OFF   3200000    // fp8 ee, dst-sorted: 800k x 64 B = 12.8M slots
#define OS_OFF   16000000   // bf16 osum: 1.6M slots
#define S_OFF    17600000   // 16
#define RP_OFF   17600016   // 50,001 (+1 pad)
#define SRCP_OFF 17650018   // 800k ints (src per sorted position)
#define POSE_OFF 18450018   // 800k ints (sorted position per orig edge)
#define DSTP_OFF 19250018   // 800k ints (dst per sorted position)
#define DEG_OFF  20050018   // 50k ints
#define WOFF_OFF 20100018   // 50k ints
#define BSUM_OFF 20150018   // 256 ints
#define MSG_OFF  20150274   // fp8 msg, dst-sorted: 800k x 64 B = 12.8M slots
// aliases (dead ranges reused):
#define H_OFF    0          // bf16 h (1.6M slots) over q (dead after k_sum)
#define F1_OFF   EE_OFF     // bf16 f1 (3.2M slots) over ee (dead after k_edge)

typedef __bf16 bf16x8 __attribute__((ext_vector_type(8)));
typedef float  f32x4  __attribute__((ext_vector_type(4)));

__device__ __forceinline__ ushort f2bf(float f) {
  uint u = __float_as_uint(f);
  uint r = (u + 0x7FFFu + ((u >> 16) & 1u)) >> 16;
  return (ushort)r;
}
__device__ __forceinline__ float bfu2f(ushort u) {
  return __uint_as_float(((uint)u) << 16);
}
__device__ __forceinline__ void unpack8(uint4 u, float (&f)[8]) {
  f[0] = __uint_as_float(u.x << 16); f[1] = __uint_as_float(u.x & 0xffff0000u);
  f[2] = __uint_as_float(u.y << 16); f[3] = __uint_as_float(u.y & 0xffff0000u);
  f[4] = __uint_as_float(u.z << 16); f[5] = __uint_as_float(u.z & 0xffff0000u);
  f[6] = __uint_as_float(u.w << 16); f[7] = __uint_as_float(u.w & 0xffff0000u);
}
__device__ __forceinline__ void unfp8(uint2 u, float (&f)[8]) {
  f[0] = __builtin_amdgcn_cvt_f32_fp8((int)u.x, 0);
  f[1] = __builtin_amdgcn_cvt_f32_fp8((int)u.x, 1);
  f[2] = __builtin_amdgcn_cvt_f32_fp8((int)u.x, 2);
  f[3] = __builtin_amdgcn_cvt_f32_fp8((int)u.x, 3);
  f[4] = __builtin_amdgcn_cvt_f32_fp8((int)u.y, 0);
  f[5] = __builtin_amdgcn_cvt_f32_fp8((int)u.y, 1);
  f[6] = __builtin_amdgcn_cvt_f32_fp8((int)u.y, 2);
  f[7] = __builtin_amdgcn_cvt_f32_fp8((int)u.y, 3);
}
__device__ __forceinline__ bf16x8 pack_bf8(float4 a, float4 b) {
  bf16x8 r;
  r[0] = (__bf16)a.x; r[1] = (__bf16)a.y; r[2] = (__bf16)a.z; r[3] = (__bf16)a.w;
  r[4] = (__bf16)b.x; r[5] = (__bf16)b.y; r[6] = (__bf16)b.z; r[7] = (__bf16)b.w;
  return r;
}
__device__ __forceinline__ uint pk_fp8(f32x4 acc) {
  uint rr = (uint)__builtin_amdgcn_cvt_pk_fp8_f32(acc[0], acc[1], 0, false);
  return (uint)__builtin_amdgcn_cvt_pk_fp8_f32(acc[2], acc[3], (int)rr, true);
}

// ---------------- QKV via MFMA: q -> bf16, k/v -> fp8 (+ deg/S zero prologue) ----------------
__global__ __launch_bounds__(256) void k_qkv_mfma(
    const float* __restrict__ x,
    const float* __restrict__ Wq, const float* __restrict__ bq,
    const float* __restrict__ Wk, const float* __restrict__ bk,
    const float* __restrict__ Wv, const float* __restrict__ bv,
    ushort* __restrict__ q, unsigned char* __restrict__ k8,
    unsigned char* __restrict__ v8,
    int* __restrict__ deg, float* __restrict__ S) {
  const int tid0 = blockIdx.x * 256 + threadIdx.x;
  if (tid0 < N_NODES) deg[tid0] = 0;
  if (tid0 < 16) S[tid0] = 0.f;

  const int lane = threadIdx.x & 63;
  const int wid  = threadIdx.x >> 6;
  const int r  = lane & 15;
  const int kg = lane >> 4;
  const float* Ws[3] = {Wq, Wk, Wv};
  const float* bs[3] = {bq, bk, bv};

  bf16x8 afrag[3][4][2];
  float  bias[3][4][4];
#pragma unroll
  for (int m = 0; m < 3; ++m)
#pragma unroll
    for (int nt = 0; nt < 4; ++nt) {
#pragma unroll
      for (int kk = 0; kk < 2; ++kk)
#pragma unroll
        for (int j = 0; j < 8; ++j)
          afrag[m][nt][kk][j] = (__bf16)Ws[m][(kk * 32 + kg * 8 + j) * 64 + nt * 16 + r];
#pragma unroll
      for (int j = 0; j < 4; ++j) bias[m][nt][j] = bs[m][nt * 16 + kg * 4 + j];
    }

  const int ntile = N_NODES / 16;  // 3125
  const int nw = gridDim.x * 4;
  for (int t = blockIdx.x * 4 + wid; t < ntile; t += nw) {
    const int base = t * 16;
    const float4* xr = reinterpret_cast<const float4*>(x + (size_t)(base + r) * 64 + kg * 8);
    const bf16x8 xf0 = pack_bf8(xr[0], xr[1]);
    const bf16x8 xf1 = pack_bf8(xr[8], xr[9]);
#pragma unroll
    for (int m = 0; m < 3; ++m) {
#pragma unroll
      for (int nt = 0; nt < 4; ++nt) {
        f32x4 acc = {bias[m][nt][0], bias[m][nt][1], bias[m][nt][2], bias[m][nt][3]};
        acc = __builtin_amdgcn_mfma_f32_16x16x32_bf16(afrag[m][nt][0], xf0, acc, 0, 0, 0);
        acc = __builtin_amdgcn_mfma_f32_16x16x32_bf16(afrag[m][nt][1], xf1, acc, 0, 0, 0);
        if (m == 0) {
          ushort4 pk;
          pk.x = f2bf(acc[0]); pk.y = f2bf(acc[1]); pk.z = f2bf(acc[2]); pk.w = f2bf(acc[3]);
          *reinterpret_cast<ushort4*>(q + (size_t)(base + r) * 64 + nt * 16 + kg * 4) = pk;
        } else {
          unsigned char* dst = (m == 1) ? k8 : v8;
          *reinterpret_cast<uint*>(dst + (size_t)(base + r) * 64 + nt * 16 + kg * 4) = pk_fp8(acc);
        }
      }
    }
  }
}

// ---------------- CSR build ----------------
__global__ __launch_bounds__(256) void k_hist(const int* __restrict__ edst,
                                              int* __restrict__ deg) {
  const int i = blockIdx.x * 256 + threadIdx.x;
  if (i < N_EDGES) atomicAdd(&deg[edst[i]], 1);
}

__global__ __launch_bounds__(256) void k_scan_a(const int* __restrict__ deg,
                                                int* __restrict__ bsum) {
  __shared__ int lds[256];
  const int i = blockIdx.x * 256 + threadIdx.x;
  lds[threadIdx.x] = (i < N_NODES) ? deg[i] : 0;
  __syncthreads();
  for (int s = 128; s > 0; s >>= 1) {
    if (threadIdx.x < s) lds[threadIdx.x] += lds[threadIdx.x + s];
    __syncthreads();
  }
  if (threadIdx.x == 0) bsum[blockIdx.x] = lds[0];
}

// finalize: inline prefix of bsum + local scan
__global__ __launch_bounds__(256) void k_scan_c(const int* __restrict__ deg,
                                                const int* __restrict__ bsum,
                                                int* __restrict__ rowptr,
                                                int* __restrict__ woff) {
  __shared__ int lds[256];
  const int t = threadIdx.x;
  lds[t] = (t < blockIdx.x) ? bsum[t] : 0;   // blockIdx.x <= 195 < 256
  __syncthreads();
  for (int s = 128; s > 0; s >>= 1) {
    if (t < s) lds[t] += lds[t + s];
    __syncthreads();
  }
  const int base0 = lds[0];
  __syncthreads();
  const int i = blockIdx.x * 256 + t;
  const int d = (i < N_NODES) ? deg[i] : 0;
  lds[t] = d;
  __syncthreads();
  for (int off = 1; off < 256; off <<= 1) {
    const int val = (t >= off) ? lds[t - off] : 0;
    __syncthreads();
    lds[t] += val;
    __syncthreads();
  }
  const int ex = base0 + lds[t] - d;
  if (i < N_NODES) { rowptr[i] = ex; woff[i] = ex; }
  if (i == N_NODES - 1) rowptr[N_NODES] = ex + d;
}

// scatter: srcp/dstp (random 4B) + pose (sequential 4B)
__global__ __launch_bounds__(256) void k_scatter(const int* __restrict__ esrc,
                                                 const int* __restrict__ edst,
                                                 int* __restrict__ woff,
                                                 int* __restrict__ srcp,
                                                 int* __restrict__ dstp,
                                                 int* __restrict__ pose) {
  const int i = blockIdx.x * 256 + threadIdx.x;
  if (i < N_EDGES) {
    const int d = edst[i];
    const int pos = atomicAdd(&woff[d], 1);
    srcp[pos] = esrc[i];
    dstp[pos] = d;
    pose[i] = pos;
  }
}

// ---------------- ee GEMM via MFMA: sequential ea reads, scattered fp8 row writes ----------------
__global__ __launch_bounds__(256) void k_ee_mfma(
    const int* __restrict__ pose, const float* __restrict__ ea,
    const float* __restrict__ We, const float* __restrict__ be,
    unsigned char* __restrict__ ee8) {
  const int lane = threadIdx.x & 63;
  const int wid  = threadIdx.x >> 6;
  const int r  = lane & 15;
  const int kg = lane >> 4;

  bf16x8 afrag[4];
  float  bias[4][4];
#pragma unroll
  for (int nt = 0; nt < 4; ++nt) {
#pragma unroll
    for (int j = 0; j < 8; ++j)
      afrag[nt][j] = (__bf16)We[(kg * 8 + j) * 64 + nt * 16 + r];
#pragma unroll
    for (int j = 0; j < 4; ++j) bias[nt][j] = be[nt * 16 + kg * 4 + j];
  }

  const int ntile = N_EDGES / 16;  // 50000
  const int nw = gridDim.x * 4;
  for (int t = blockIdx.x * 4 + wid; t < ntile; t += nw) {
    const int base = t * 16;
    const int pos = pose[base + r];
    const float4* ar = reinterpret_cast<const float4*>(ea + (size_t)(base + r) * 32 + kg * 8);
    const bf16x8 bfrag = pack_bf8(ar[0], ar[1]);
#pragma unroll
    for (int nt = 0; nt < 4; ++nt) {
      f32x4 acc = {bias[nt][0], bias[nt][1], bias[nt][2], bias[nt][3]};
      acc = __builtin_amdgcn_mfma_f32_16x16x32_bf16(afrag[nt], bfrag, acc, 0, 0, 0);
      *reinterpret_cast<uint*>(ee8 + (size_t)pos * 64 + nt * 16 + kg * 4) = pk_fp8(acc);
    }
  }
}

// ---------------- edge pass: position-streaming, msg8[p] = fp8(w*(v+ee)), S += w ----------------
// lane=(pos-slot, head); 8 positions per wave-trip, fully independent. No per-node state.
__global__ __launch_bounds__(256) void k_edge(
    const int* __restrict__ srcp, const int* __restrict__ dstp,
    const unsigned char* __restrict__ ee8,
    const ushort* __restrict__ qb, const unsigned char* __restrict__ k8,
    const unsigned char* __restrict__ v8,
    unsigned char* __restrict__ msg8, float* __restrict__ S) {
  const int lane = threadIdx.x & 63;
  const int wid  = threadIdx.x >> 6;
  const int h = lane & 7, ei = lane >> 3;
  float sacc = 0.f;
  const int nw = gridDim.x * 4;
  const int ntrip = N_EDGES / 8;  // 100000 exact
  for (int t = blockIdx.x * 4 + wid; t < ntrip; t += nw) {
    const int p = t * 8 + ei;
    const int src = srcp[p];
    const int dst = dstp[p];
    float qv[8], kv[8], vv[8], ev[8];
    unpack8(*reinterpret_cast<const uint4*>(qb + (size_t)dst * 64 + h * 8), qv);
    unfp8(*reinterpret_cast<const uint2*>(k8 + (size_t)src * 64 + h * 8), kv);
    unfp8(*reinterpret_cast<const uint2*>(v8 + (size_t)src * 64 + h * 8), vv);
    unfp8(*reinterpret_cast<const uint2*>(ee8 + (size_t)p * 64 + h * 8), ev);
    float sc = 0.f;
#pragma unroll
    for (int i = 0; i < 8; ++i) sc = fmaf(qv[i], kv[i] + ev[i], sc);
    const float w = __expf(sc * 0.3535533905932738f);  // 1/sqrt(8)
    sacc += w;
    f32x4 m0 = {w * (vv[0] + ev[0]), w * (vv[1] + ev[1]),
                w * (vv[2] + ev[2]), w * (vv[3] + ev[3])};
    f32x4 m1 = {w * (vv[4] + ev[4]), w * (vv[5] + ev[5]),
                w * (vv[6] + ev[6]), w * (vv[7] + ev[7])};
    *reinterpret_cast<uint2*>(msg8 + (size_t)p * 64 + h * 8) =
        make_uint2(pk_fp8(m0), pk_fp8(m1));
  }
  sacc += __shfl_xor(sacc, 8);
  sacc += __shfl_xor(sacc, 16);
  sacc += __shfl_xor(sacc, 32);
  if (ei == 0) atomicAdd(&S[h], sacc);
}

// ---------------- segmented sum: osum[n] = self-loop + sum msg8 rows ----------------
__global__ __launch_bounds__(256) void k_sum(
    const int* __restrict__ rowptr, const unsigned char* __restrict__ msg8,
    const ushort* __restrict__ qb, const unsigned char* __restrict__ k8,
    const unsigned char* __restrict__ v8, const float* __restrict__ be,
    ushort* __restrict__ osum, float* __restrict__ S) {
  const int lane = threadIdx.x & 63;
  const int wid  = threadIdx.x >> 6;
  const int h = lane & 7, ei = lane >> 3;
  float bes[8];
#pragma unroll
  for (int i = 0; i < 8; ++i) bes[i] = be[h * 8 + i];
  float sacc = 0.f;
  const int nw = gridDim.x * 4;
  for (int n = blockIdx.x * 4 + wid; n < N_NODES; n += nw) {
    const int beg = rowptr[n], end = rowptr[n + 1];
    float macc[8];
#pragma unroll
    for (int i = 0; i < 8; ++i) macc[i] = 0.f;
    if (ei == 0) {  // self loop: ea=0 -> ee=be
      float qv[8], kv[8], vv[8];
      unpack8(*reinterpret_cast<const uint4*>(qb + (size_t)n * 64 + h * 8), qv);
      unfp8(*reinterpret_cast<const uint2*>(k8 + (size_t)n * 64 + h * 8), kv);
      unfp8(*reinterpret_cast<const uint2*>(v8 + (size_t)n * 64 + h * 8), vv);
      float sc = 0.f;
#pragma unroll
      for (int i = 0; i < 8; ++i) sc = fmaf(qv[i], kv[i] + bes[i], sc);
      const float w = __expf(sc * 0.3535533905932738f);
      sacc += w;
#pragma unroll
      for (int i = 0; i < 8; ++i) macc[i] = w * (vv[i] + bes[i]);
    }
    for (int p = beg + ei; p < end; p += 8) {
      float mv[8];
      unfp8(*reinterpret_cast<const uint2*>(msg8 + (size_t)p * 64 + h * 8), mv);
#pragma unroll
      for (int i = 0; i < 8; ++i) macc[i] += mv[i];
    }
#pragma unroll
    for (int i = 0; i < 8; ++i) {
      macc[i] += __shfl_xor(macc[i], 8);
      macc[i] += __shfl_xor(macc[i], 16);
      macc[i] += __shfl_xor(macc[i], 32);
    }
    if (ei == 0) {
      uint pk[4];
#pragma unroll
      for (int i = 0; i < 4; ++i)
        pk[i] = (uint)f2bf(macc[2 * i]) | ((uint)f2bf(macc[2 * i + 1]) << 16);
      *reinterpret_cast<uint4*>(osum + (size_t)n * 64 + h * 8) =
          make_uint4(pk[0], pk[1], pk[2], pk[3]);
    }
  }
  sacc += __shfl_xor(sacc, 8);
  sacc += __shfl_xor(sacc, 16);
  sacc += __shfl_xor(sacc, 32);
  if (ei == 0) atomicAdd(&S[h], sacc);
}

// ---------------- LN1 via MFMA: h = LN(x + (osum/(S*cnt)) @ Wo + bo) -> bf16 ----------------
__global__ __launch_bounds__(256) void k_ln1_mfma(
    const ushort* __restrict__ osum, const int* __restrict__ rowptr,
    const float* __restrict__ S, const float* __restrict__ x,
    const float* __restrict__ Wo, const float* __restrict__ bo,
    const float* __restrict__ g1, const float* __restrict__ b1,
    ushort* __restrict__ h) {
  const int lane = threadIdx.x & 63;
  const int wid  = threadIdx.x >> 6;
  const int r  = lane & 15;
  const int kg = lane >> 4;

  bf16x8 afrag[4][2];
  float bias[4][4], g1f[4][4], b1f[4][4];
#pragma unroll
  for (int nt = 0; nt < 4; ++nt) {
#pragma unroll
    for (int kk = 0; kk < 2; ++kk)
#pragma unroll
      for (int j = 0; j < 8; ++j)
        afrag[nt][kk][j] = (__bf16)Wo[(kk * 32 + kg * 8 + j) * 64 + nt * 16 + r];
#pragma unroll
    for (int j = 0; j < 4; ++j) {
      bias[nt][j] = bo[nt * 16 + kg * 4 + j];
      g1f[nt][j]  = g1[nt * 16 + kg * 4 + j];
      b1f[nt][j]  = b1[nt * 16 + kg * 4 + j];
    }
  }
  float invSv[8];
#pragma unroll
  for (int i = 0; i < 8; ++i) invSv[i] = 1.0f / S[i];

  const int ntile = N_NODES / 16;  // 3125
  const int nw = gridDim.x * 4;
  for (int t = blockIdx.x * 4 + wid; t < ntile; t += nw) {
    const int node = t * 16 + r;
    const float invc = 1.0f / (float)(rowptr[node + 1] - rowptr[node] + 1);
    bf16x8 bfrag[2];
#pragma unroll
    for (int kk = 0; kk < 2; ++kk) {
      float tmp[8];
      unpack8(*reinterpret_cast<const uint4*>(osum + (size_t)node * 64 + kk * 32 + kg * 8), tmp);
      const float sc = invSv[kk * 4 + kg] * invc;
      bf16x8 bf;
#pragma unroll
      for (int e = 0; e < 8; ++e) bf[e] = (__bf16)(tmp[e] * sc);
      bfrag[kk] = bf;
    }
    float tv[4][4];
    float sum = 0.f;
#pragma unroll
    for (int nt = 0; nt < 4; ++nt) {
      f32x4 acc = {bias[nt][0], bias[nt][1], bias[nt][2], bias[nt][3]};
      acc = __builtin_amdgcn_mfma_f32_16x16x32_bf16(afrag[nt][0], bfrag[0], acc, 0, 0, 0);
      acc = __builtin_amdgcn_mfma_f32_16x16x32_bf16(afrag[nt][1], bfrag[1], acc, 0, 0, 0);
      const float4 xv = *reinterpret_cast<const float4*>(x + (size_t)node * 64 + nt * 16 + kg * 4);
      tv[nt][0] = acc[0] + xv.x; tv[nt][1] = acc[1] + xv.y;
      tv[nt][2] = acc[2] + xv.z; tv[nt][3] = acc[3] + xv.w;
      sum += (tv[nt][0] + tv[nt][1]) + (tv[nt][2] + tv[nt][3]);
    }
    sum += __shfl_xor(sum, 16);
    sum += __shfl_xor(sum, 32);
    const float m = sum * (1.0f / 64.0f);
    float var = 0.f;
#pragma unroll
    for (int nt = 0; nt < 4; ++nt)
#pragma unroll
      for (int j = 0; j < 4; ++j) { const float d = tv[nt][j] - m; var = fmaf(d, d, var); }
    var += __shfl_xor(var, 16);
    var += __shfl_xor(var, 32);
    const float rinv = rsqrtf(var * (1.0f / 64.0f) + 1e-5f);
#pragma unroll
    for (int nt = 0; nt < 4; ++nt) {
      ushort4 pk;
      pk.x = f2bf((tv[nt][0] - m) * rinv * g1f[nt][0] + b1f[nt][0]);
      pk.y = f2bf((tv[nt][1] - m) * rinv * g1f[nt][1] + b1f[nt][1]);
      pk.z = f2bf((tv[nt][2] - m) * rinv * g1f[nt][2] + b1f[nt][2]);
      pk.w = f2bf((tv[nt][3] - m) * rinv * g1f[nt][3] + b1f[nt][3]);
      *reinterpret_cast<ushort4*>(h + (size_t)node * 64 + nt * 16 + kg * 4) = pk;
    }
  }
}

// ---------------- FFN1 via MFMA: f1 = gelu(h @ Wf1 + bf1) -> bf16 ----------------
__global__ __launch_bounds__(256) void k_ffn1_mfma(
    const ushort* __restrict__ h, const float* __restrict__ Wf1,
    const float* __restrict__ bf1, ushort* __restrict__ f1) {
  const int lane = threadIdx.x & 63;
  const int wid  = threadIdx.x >> 6;
  const int r  = lane & 15;
  const int kg = lane >> 4;

  bf16x8 afrag[8][2];
  float bias[8][4];
#pragma unroll
  for (int nt = 0; nt < 8; ++nt) {
#pragma unroll
    for (int kk = 0; kk < 2; ++kk)
#pragma unroll
      for (int j = 0; j < 8; ++j)
        afrag[nt][kk][j] = (__bf16)Wf1[(kk * 32 + kg * 8 + j) * 128 + nt * 16 + r];
#pragma unroll
    for (int j = 0; j < 4; ++j) bias[nt][j] = bf1[nt * 16 + kg * 4 + j];
  }

  const int ntile = N_NODES / 16;  // 3125
  const int nw = gridDim.x * 4;
  for (int t = blockIdx.x * 4 + wid; t < ntile; t += nw) {
    const int node = t * 16 + r;
    const bf16x8 bf0 = *reinterpret_cast<const bf16x8*>(h + (size_t)node * 64 + kg * 8);
    const bf16x8 bf1g = *reinterpret_cast<const bf16x8*>(h + (size_t)node * 64 + 32 + kg * 8);
#pragma unroll
    for (int nt = 0; nt < 8; ++nt) {
      f32x4 acc = {bias[nt][0], bias[nt][1], bias[nt][2], bias[nt][3]};
      acc = __builtin_amdgcn_mfma_f32_16x16x32_bf16(afrag[nt][0], bf0, acc, 0, 0, 0);
      acc = __builtin_amdgcn_mfma_f32_16x16x32_bf16(afrag[nt][1], bf1g, acc, 0, 0, 0);
      ushort4 pk;
      pk.x = f2bf(0.5f * acc[0] * (1.0f + erff(acc[0] * 0.7071067811865475f)));
      pk.y = f2bf(0.5f * acc[1] * (1.0f + erff(acc[1] * 0.7071067811865475f)));
      pk.z = f2bf(0.5f * acc[2] * (1.0f + erff(acc[2] * 0.7071067811865475f)));
      pk.w = f2bf(0.5f * acc[3] * (1.0f + erff(acc[3] * 0.7071067811865475f)));
      *reinterpret_cast<ushort4*>(f1 + (size_t)node * 128 + nt * 16 + kg * 4) = pk;
    }
  }
}

// ---------------- FFN2 via MFMA + residual + LN2 -> out (f32) ----------------
__global__ __launch_bounds__(256) void k_ffn2_mfma(
    const ushort* __restrict__ f1, const ushort* __restrict__ h,
    const float* __restrict__ Wf2, const float* __restrict__ bf2,
    const float* __restrict__ g2, const float* __restrict__ b2,
    float* __restrict__ out) {
  const int lane = threadIdx.x & 63;
  const int wid  = threadIdx.x >> 6;
  const int r  = lane & 15;
  const int kg = lane >> 4;

  bf16x8 afrag[4][4];
  float bias[4][4], g2f[4][4], b2f[4][4];
#pragma unroll
  for (int nt = 0; nt < 4; ++nt) {
#pragma unroll
    for (int kk = 0; kk < 4; ++kk)
#pragma unroll
      for (int j = 0; j < 8; ++j)
        afrag[nt][kk][j] = (__bf16)Wf2[(kk * 32 + kg * 8 + j) * 64 + nt * 16 + r];
#pragma unroll
    for (int j = 0; j < 4; ++j) {
      bias[nt][j] = bf2[nt * 16 + kg * 4 + j];
      g2f[nt][j]  = g2[nt * 16 + kg * 4 + j];
      b2f[nt][j]  = b2[nt * 16 + kg * 4 + j];
    }
  }

  const int ntile = N_NODES / 16;  // 3125
  const int nw = gridDim.x * 4;
  for (int t = blockIdx.x * 4 + wid; t < ntile; t += nw) {
    const int node = t * 16 + r;
    bf16x8 bfrag[4];
#pragma unroll
    for (int kk = 0; kk < 4; ++kk)
      bfrag[kk] = *reinterpret_cast<const bf16x8*>(f1 + (size_t)node * 128 + kk * 32 + kg * 8);
    float tv[4][4];
    float sum = 0.f;
#pragma unroll
    for (int nt = 0; nt < 4; ++nt) {
      f32x4 acc = {bias[nt][0], bias[nt][1], bias[nt][2], bias[nt][3]};
      acc = __builtin_amdgcn_mfma_f32_16x16x32_bf16(afrag[nt][0], bfrag[0], acc, 0, 0, 0);
      acc = __builtin_amdgcn_mfma_f32_16x16x32_bf16(afrag[nt][1], bfrag[1], acc, 0, 0, 0);
      acc = __builtin_amdgcn_mfma_f32_16x16x32_bf16(afrag[nt][2], bfrag[2], acc, 0, 0, 0);
      acc = __builtin_amdgcn_mfma_f32_16x16x32_bf16(afrag[nt][3], bfrag[3], acc, 0, 0, 0);
      const ushort4 hv = *reinterpret_cast<const ushort4*>(h + (size_t)node * 64 + nt * 16 + kg * 4);
      tv[nt][0] = acc[0] + bfu2f(hv.x); tv[nt][1] = acc[1] + bfu2f(hv.y);
      tv[nt][2] = acc[2] + bfu2f(hv.z); tv[nt][3] = acc[3] + bfu2f(hv.w);
      sum += (tv[nt][0] + tv[nt][1]) + (tv[nt][2] + tv[nt][3]);
    }
    sum += __shfl_xor(sum, 16);
    sum += __shfl_xor(sum, 32);
    const float m = sum * (1.0f / 64.0f);
    float var = 0.f;
#pragma unroll
    for (int nt = 0; nt < 4; ++nt)
#pragma unroll
      for (int j = 0; j < 4; ++j) { const float d = tv[nt][j] - m; var = fmaf(d, d, var); }
    var += __shfl_xor(var, 16);
    var += __shfl_xor(var, 32);
    const float rinv = rsqrtf(var * (1.0f / 64.0f) + 1e-5f);
#pragma unroll
    for (int nt = 0; nt < 4; ++nt) {
      float4 o;
      o.x = (tv[nt][0] - m) * rinv * g2f[nt][0] + b2f[nt][0];
      o.y = (tv[nt][1] - m) * rinv * g2f[nt][1] + b2f[nt][1];
      o.z = (tv[nt][2] - m) * rinv * g2f[nt][2] + b2f[nt][2];
      o.w = (tv[nt][3] - m) * rinv * g2f[nt][3] + b2f[nt][3];
      *reinterpret_cast<float4*>(out + (size_t)node * 64 + nt * 16 + kg * 4) = o;
    }
  }
}

extern "C" void kernel_launch(void* const* d_in, const int* in_sizes, int n_in,
                              void* d_out, int out_size, void* d_ws, size_t ws_size,
                              hipStream_t stream) {
  const float* x    = (const float*)d_in[0];
  const int*   ei   = (const int*)d_in[1];
  const int*   esrc = ei;
  const int*   edst = ei + N_EDGES;
  const float* ea   = (const float*)d_in[2];
  const float* Wq   = (const float*)d_in[3];
  const float* bq   = (const float*)d_in[4];
  const float* Wk   = (const float*)d_in[5];
  const float* bk   = (const float*)d_in[6];
  const float* Wv   = (const float*)d_in[7];
  const float* bv   = (const float*)d_in[8];
  const float* We   = (const float*)d_in[9];
  const float* be   = (const float*)d_in[10];
  const float* Wo   = (const float*)d_in[11];
  const float* bo   = (const float*)d_in[12];
  const float* g1   = (const float*)d_in[13];
  const float* b1   = (const float*)d_in[14];
  const float* g2   = (const float*)d_in[15];
  const float* b2   = (const float*)d_in[16];
  const float* Wf1  = (const float*)d_in[17];
  const float* bf1  = (const float*)d_in[18];
  const float* Wf2  = (const float*)d_in[19];
  const float* bf2  = (const float*)d_in[20];

  float* ws    = (float*)d_ws;
  ushort* q    = (ushort*)(ws + Q_OFF);
  unsigned char* k8  = (unsigned char*)(ws + K8_OFF);
  unsigned char* v8  = (unsigned char*)(ws + V8_OFF);
  unsigned char* ee8 = (unsigned char*)(ws + EE_OFF);
  ushort* osum = (ushort*)(ws + OS_OFF);
  float* S     = ws + S_OFF;
  int*   rowptr = (int*)(ws + RP_OFF);
  int*   srcp   = (int*)(ws + SRCP_OFF);
  int*   pose   = (int*)(ws + POSE_OFF);
  int*   dstp   = (int*)(ws + DSTP_OFF);
  int*   deg    = (int*)(ws + DEG_OFF);
  int*   woff   = (int*)(ws + WOFF_OFF);
  int*   bsum   = (int*)(ws + BSUM_OFF);
  unsigned char* msg8 = (unsigned char*)(ws + MSG_OFF);
  ushort* h    = (ushort*)(ws + H_OFF);
  ushort* f1   = (ushort*)(ws + F1_OFF);
  float* out   = (float*)d_out;

  const dim3 B(256);
  const int edgeBlocks = (N_EDGES + 255) / 256;  // 3125

  k_qkv_mfma<<<dim3(256), B, 0, stream>>>(x, Wq, bq, Wk, bk, Wv, bv, q, k8, v8, deg, S);
  k_hist<<<dim3(edgeBlocks), B, 0, stream>>>(edst, deg);
  k_scan_a<<<dim3(NB), B, 0, stream>>>(deg, bsum);
  k_scan_c<<<dim3(NB), B, 0, stream>>>(deg, bsum, rowptr, woff);
  k_scatter<<<dim3(edgeBlocks), B, 0, stream>>>(esrc, edst, woff, srcp, dstp, pose);
  k_ee_mfma<<<dim3(1024), B, 0, stream>>>(pose, ea, We, be, ee8);
  k_edge<<<dim3(2048), B, 0, stream>>>(srcp, dstp, ee8, q, k8, v8, msg8, S);
  k_sum<<<dim3(1024), B, 0, stream>>>(rowptr, msg8, q, k8, v8, be, osum, S);
  k_ln1_mfma<<<dim3(256), B, 0, stream>>>(osum, rowptr, S, x, Wo, bo, g1, b1, h);
  k_ffn1_mfma<<<dim3(256), B, 0, stream>>>(h, Wf1, bf1, f1);
  k_ffn2_mfma<<<dim3(256), B, 0, stream>>>(f1, h, Wf2, bf2, g2, b2, out);
}

// Round 15
// 268.038 us; speedup vs baseline: 1.4841x; 1.4841x over previous
//
#include <hip/hip_runtime.h>
#include <hip/hip_bf16.h>
#include <math.h>

#define N_NODES 50000
#define N_EDGES 800000
#define D 64
#define ED 32
#define NB 196   // node blocks = ceil(50000/256)

// ws layout (float-slot offsets). Total ~19.35M slots = 77.4 MB.
#define Q_OFF    0          // bf16 q (1.6M slots)
#define KV8_OFF  1600000    // fp8 k+v interleaved: 50k x 128 B = 1.6M slots
#define EE_OFF   3200000    // fp8 ee, dst-sorted: 800k x 64 B = 12.8M slots
#define OS_OFF   16000000   // bf16 osum: 1.6M slots
#define S_OFF    17600000   // 16
#define RP_OFF   17600016   // 50,001 (+1 pad)
#define SRCP_OFF 17650018   // 800k ints (src per sorted position)
#define POSE_OFF 18450018   // 800k ints (sorted position per orig edge)
#define DEG_OFF  19250018   // 50k ints
#define WOFF_OFF 19300018   // 50k ints
#define BSUM_OFF 19350018   // 256 ints
// aliases (dead ranges reused):
#define H_OFF    0          // bf16 h (1.6M slots) over q (dead after gather)
#define F1_OFF   EE_OFF     // bf16 f1 (3.2M slots) over ee (dead after gather)

typedef __bf16 bf16x8 __attribute__((ext_vector_type(8)));
typedef float  f32x4  __attribute__((ext_vector_type(4)));

__device__ __forceinline__ ushort f2bf(float f) {
  uint u = __float_as_uint(f);
  uint r = (u + 0x7FFFu + ((u >> 16) & 1u)) >> 16;
  return (ushort)r;
}
__device__ __forceinline__ float bfu2f(ushort u) {
  return __uint_as_float(((uint)u) << 16);
}
__device__ __forceinline__ void unpack8(uint4 u, float (&f)[8]) {
  f[0] = __uint_as_float(u.x << 16); f[1] = __uint_as_float(u.x & 0xffff0000u);
  f[2] = __uint_as_float(u.y << 16); f[3] = __uint_as_float(u.y & 0xffff0000u);
  f[4] = __uint_as_float(u.z << 16); f[5] = __uint_as_float(u.z & 0xffff0000u);
  f[6] = __uint_as_float(u.w << 16); f[7] = __uint_as_float(u.w & 0xffff0000u);
}
__device__ __forceinline__ void unfp8(uint2 u, float (&f)[8]) {
  f[0] = __builtin_amdgcn_cvt_f32_fp8((int)u.x, 0);
  f[1] = __builtin_amdgcn_cvt_f32_fp8((int)u.x, 1);
  f[2] = __builtin_amdgcn_cvt_f32_fp8((int)u.x, 2);
  f[3] = __builtin_amdgcn_cvt_f32_fp8((int)u.x, 3);
  f[4] = __builtin_amdgcn_cvt_f32_fp8((int)u.y, 0);
  f[5] = __builtin_amdgcn_cvt_f32_fp8((int)u.y, 1);
  f[6] = __builtin_amdgcn_cvt_f32_fp8((int)u.y, 2);
  f[7] = __builtin_amdgcn_cvt_f32_fp8((int)u.y, 3);
}
__device__ __forceinline__ bf16x8 pack_bf8(float4 a, float4 b) {
  bf16x8 r;
  r[0] = (__bf16)a.x; r[1] = (__bf16)a.y; r[2] = (__bf16)a.z; r[3] = (__bf16)a.w;
  r[4] = (__bf16)b.x; r[5] = (__bf16)b.y; r[6] = (__bf16)b.z; r[7] = (__bf16)b.w;
  return r;
}
__device__ __forceinline__ uint pk_fp8(f32x4 acc) {
  uint rr = (uint)__builtin_amdgcn_cvt_pk_fp8_f32(acc[0], acc[1], 0, false);
  return (uint)__builtin_amdgcn_cvt_pk_fp8_f32(acc[2], acc[3], (int)rr, true);
}

// ---------------- QKV via MFMA: q -> bf16, k/v -> interleaved fp8 kv8 ----------------
// kv8 layout per node (128 B): for head h, bytes [h*16 .. h*16+8) = k, [h*16+8 .. h*16+16) = v.
__global__ __launch_bounds__(256) void k_qkv_mfma(
    const float* __restrict__ x,
    const float* __restrict__ Wq, const float* __restrict__ bq,
    const float* __restrict__ Wk, const float* __restrict__ bk,
    const float* __restrict__ Wv, const float* __restrict__ bv,
    ushort* __restrict__ q, unsigned char* __restrict__ kv8,
    int* __restrict__ deg, float* __restrict__ S) {
  const int tid0 = blockIdx.x * 256 + threadIdx.x;
  if (tid0 < N_NODES) deg[tid0] = 0;
  if (tid0 < 16) S[tid0] = 0.f;

  const int lane = threadIdx.x & 63;
  const int wid  = threadIdx.x >> 6;
  const int r  = lane & 15;
  const int kg = lane >> 4;
  const float* Ws[3] = {Wq, Wk, Wv};
  const float* bs[3] = {bq, bk, bv};

  bf16x8 afrag[3][4][2];
  float  bias[3][4][4];
#pragma unroll
  for (int m = 0; m < 3; ++m)
#pragma unroll
    for (int nt = 0; nt < 4; ++nt) {
#pragma unroll
      for (int kk = 0; kk < 2; ++kk)
#pragma unroll
        for (int j = 0; j < 8; ++j)
          afrag[m][nt][kk][j] = (__bf16)Ws[m][(kk * 32 + kg * 8 + j) * 64 + nt * 16 + r];
#pragma unroll
      for (int j = 0; j < 4; ++j) bias[m][nt][j] = bs[m][nt * 16 + kg * 4 + j];
    }

  const int ntile = N_NODES / 16;  // 3125
  const int nw = gridDim.x * 4;
  for (int t = blockIdx.x * 4 + wid; t < ntile; t += nw) {
    const int base = t * 16;
    const float4* xr = reinterpret_cast<const float4*>(x + (size_t)(base + r) * 64 + kg * 8);
    const bf16x8 xf0 = pack_bf8(xr[0], xr[1]);
    const bf16x8 xf1 = pack_bf8(xr[8], xr[9]);
#pragma unroll
    for (int m = 0; m < 3; ++m) {
#pragma unroll
      for (int nt = 0; nt < 4; ++nt) {
        f32x4 acc = {bias[m][nt][0], bias[m][nt][1], bias[m][nt][2], bias[m][nt][3]};
        acc = __builtin_amdgcn_mfma_f32_16x16x32_bf16(afrag[m][nt][0], xf0, acc, 0, 0, 0);
        acc = __builtin_amdgcn_mfma_f32_16x16x32_bf16(afrag[m][nt][1], xf1, acc, 0, 0, 0);
        if (m == 0) {
          ushort4 pk;
          pk.x = f2bf(acc[0]); pk.y = f2bf(acc[1]); pk.z = f2bf(acc[2]); pk.w = f2bf(acc[3]);
          *reinterpret_cast<ushort4*>(q + (size_t)(base + r) * 64 + nt * 16 + kg * 4) = pk;
        } else {
          // feature f = nt*16 + kg*4 .. +4; head = f>>3; byte within head-k/v = f&7
          const int sub = (m == 1) ? 0 : 8;
          const size_t off = (size_t)(base + r) * 128 +
                             (size_t)(nt * 2 + (kg >> 1)) * 16 + sub + (kg & 1) * 4;
          *reinterpret_cast<uint*>(kv8 + off) = pk_fp8(acc);
        }
      }
    }
  }
}

// ---------------- CSR build ----------------
__global__ __launch_bounds__(256) void k_hist(const int* __restrict__ edst,
                                              int* __restrict__ deg) {
  const int i = blockIdx.x * 256 + threadIdx.x;
  if (i < N_EDGES) atomicAdd(&deg[edst[i]], 1);
}

__global__ __launch_bounds__(256) void k_scan_a(const int* __restrict__ deg,
                                                int* __restrict__ bsum) {
  __shared__ int lds[256];
  const int i = blockIdx.x * 256 + threadIdx.x;
  lds[threadIdx.x] = (i < N_NODES) ? deg[i] : 0;
  __syncthreads();
  for (int s = 128; s > 0; s >>= 1) {
    if (threadIdx.x < s) lds[threadIdx.x] += lds[threadIdx.x + s];
    __syncthreads();
  }
  if (threadIdx.x == 0) bsum[blockIdx.x] = lds[0];
}

// finalize: inline prefix of bsum + local scan
__global__ __launch_bounds__(256) void k_scan_c(const int* __restrict__ deg,
                                                const int* __restrict__ bsum,
                                                int* __restrict__ rowptr,
                                                int* __restrict__ woff) {
  __shared__ int lds[256];
  const int t = threadIdx.x;
  lds[t] = (t < blockIdx.x) ? bsum[t] : 0;   // blockIdx.x <= 195 < 256
  __syncthreads();
  for (int s = 128; s > 0; s >>= 1) {
    if (t < s) lds[t] += lds[t + s];
    __syncthreads();
  }
  const int base0 = lds[0];
  __syncthreads();
  const int i = blockIdx.x * 256 + t;
  const int d = (i < N_NODES) ? deg[i] : 0;
  lds[t] = d;
  __syncthreads();
  for (int off = 1; off < 256; off <<= 1) {
    const int val = (t >= off) ? lds[t - off] : 0;
    __syncthreads();
    lds[t] += val;
    __syncthreads();
  }
  const int ex = base0 + lds[t] - d;
  if (i < N_NODES) { rowptr[i] = ex; woff[i] = ex; }
  if (i == N_NODES - 1) rowptr[N_NODES] = ex + d;
}

// scatter: srcp (random 4B) + pose (sequential 4B)
__global__ __launch_bounds__(256) void k_scatter(const int* __restrict__ esrc,
                                                 const int* __restrict__ edst,
                                                 int* __restrict__ woff,
                                                 int* __restrict__ srcp,
                                                 int* __restrict__ pose) {
  const int i = blockIdx.x * 256 + threadIdx.x;
  if (i < N_EDGES) {
    const int pos = atomicAdd(&woff[edst[i]], 1);
    srcp[pos] = esrc[i];
    pose[i] = pos;
  }
}

// ---------------- ee GEMM via MFMA: sequential ea reads, scattered fp8 row writes ----------------
__global__ __launch_bounds__(256) void k_ee_mfma(
    const int* __restrict__ pose, const float* __restrict__ ea,
    const float* __restrict__ We, const float* __restrict__ be,
    unsigned char* __restrict__ ee8) {
  const int lane = threadIdx.x & 63;
  const int wid  = threadIdx.x >> 6;
  const int r  = lane & 15;
  const int kg = lane >> 4;

  bf16x8 afrag[4];
  float  bias[4][4];
#pragma unroll
  for (int nt = 0; nt < 4; ++nt) {
#pragma unroll
    for (int j = 0; j < 8; ++j)
      afrag[nt][j] = (__bf16)We[(kg * 8 + j) * 64 + nt * 16 + r];
#pragma unroll
    for (int j = 0; j < 4; ++j) bias[nt][j] = be[nt * 16 + kg * 4 + j];
  }

  const int ntile = N_EDGES / 16;  // 50000
  const int nw = gridDim.x * 4;
  for (int t = blockIdx.x * 4 + wid; t < ntile; t += nw) {
    const int base = t * 16;
    const int pos = pose[base + r];
    const float4* ar = reinterpret_cast<const float4*>(ea + (size_t)(base + r) * 32 + kg * 8);
    const bf16x8 bfrag = pack_bf8(ar[0], ar[1]);
#pragma unroll
    for (int nt = 0; nt < 4; ++nt) {
      f32x4 acc = {bias[nt][0], bias[nt][1], bias[nt][2], bias[nt][3]};
      acc = __builtin_amdgcn_mfma_f32_16x16x32_bf16(afrag[nt], bfrag, acc, 0, 0, 0);
      *reinterpret_cast<uint*>(ee8 + (size_t)pos * 64 + nt * 16 + kg * 4) = pk_fp8(acc);
    }
  }
}

// ---------------- gather: wave per node, lane=(edge-slot, head), ONE kv load/edge ----------------
__global__ __launch_bounds__(256) void k_gather(
    const int* __restrict__ rowptr, const int* __restrict__ srcp,
    const unsigned char* __restrict__ ee8,
    const ushort* __restrict__ qb, const unsigned char* __restrict__ kv8,
    const float* __restrict__ be,
    ushort* __restrict__ osum, float* __restrict__ S) {
  const int lane = threadIdx.x & 63;
  const int wid  = threadIdx.x >> 6;
  const int h = lane & 7, ei = lane >> 3;
  float bes[8];
#pragma unroll
  for (int i = 0; i < 8; ++i) bes[i] = be[h * 8 + i];
  float sacc = 0.f;
  const int nw = gridDim.x * 4;
  for (int n = blockIdx.x * 4 + wid; n < N_NODES; n += nw) {
    const int beg = rowptr[n], end = rowptr[n + 1];
    float qv[8];
    unpack8(*reinterpret_cast<const uint4*>(qb + (size_t)n * 64 + h * 8), qv);
    float macc[8];
#pragma unroll
    for (int i = 0; i < 8; ++i) macc[i] = 0.f;
    if (ei == 0) {  // self loop: ea=0 -> ee=be
      float kv[8], vv[8];
      const uint4 kvl = *reinterpret_cast<const uint4*>(kv8 + (size_t)n * 128 + h * 16);
      unfp8(make_uint2(kvl.x, kvl.y), kv);
      unfp8(make_uint2(kvl.z, kvl.w), vv);
      float sc = 0.f;
#pragma unroll
      for (int i = 0; i < 8; ++i) sc = fmaf(qv[i], kv[i] + bes[i], sc);
      const float w = __expf(sc * 0.3535533905932738f);
      sacc += w;
#pragma unroll
      for (int i = 0; i < 8; ++i) macc[i] = w * (vv[i] + bes[i]);
    }
    int p = beg + ei;
    int src = (p < end) ? srcp[p] : 0;
    for (; p < end; p += 8) {
      const int nsrc = (p + 8 < end) ? srcp[p + 8] : 0;
      float ev[8], kv[8], vv[8];
      unfp8(*reinterpret_cast<const uint2*>(ee8 + (size_t)p * 64 + h * 8), ev);
      const uint4 kvl = *reinterpret_cast<const uint4*>(kv8 + (size_t)src * 128 + h * 16);
      unfp8(make_uint2(kvl.x, kvl.y), kv);
      unfp8(make_uint2(kvl.z, kvl.w), vv);
      float sc = 0.f;
#pragma unroll
      for (int i = 0; i < 8; ++i) sc = fmaf(qv[i], kv[i] + ev[i], sc);
      const float w = __expf(sc * 0.3535533905932738f);
      sacc += w;
#pragma unroll
      for (int i = 0; i < 8; ++i) macc[i] = fmaf(w, vv[i] + ev[i], macc[i]);
      src = nsrc;
    }
#pragma unroll
    for (int i = 0; i < 8; ++i) {
      macc[i] += __shfl_xor(macc[i], 8);
      macc[i] += __shfl_xor(macc[i], 16);
      macc[i] += __shfl_xor(macc[i], 32);
    }
    if (ei == 0) {
      uint pk[4];
#pragma unroll
      for (int i = 0; i < 4; ++i)
        pk[i] = (uint)f2bf(macc[2 * i]) | ((uint)f2bf(macc[2 * i + 1]) << 16);
      *reinterpret_cast<uint4*>(osum + (size_t)n * 64 + h * 8) =
          make_uint4(pk[0], pk[1], pk[2], pk[3]);
    }
  }
  sacc += __shfl_xor(sacc, 8);
  sacc += __shfl_xor(sacc, 16);
  sacc += __shfl_xor(sacc, 32);
  if (ei == 0) atomicAdd(&S[h], sacc);
}

// ---------------- LN1 via MFMA: h = LN(x + (osum/(S*cnt)) @ Wo + bo) -> bf16 ----------------
__global__ __launch_bounds__(256) void k_ln1_mfma(
    const ushort* __restrict__ osum, const int* __restrict__ rowptr,
    const float* __restrict__ S, const float* __restrict__ x,
    const float* __restrict__ Wo, const float* __restrict__ bo,
    const float* __restrict__ g1, const float* __restrict__ b1,
    ushort* __restrict__ h) {
  const int lane = threadIdx.x & 63;
  const int wid  = threadIdx.x >> 6;
  const int r  = lane & 15;
  const int kg = lane >> 4;

  bf16x8 afrag[4][2];
  float bias[4][4], g1f[4][4], b1f[4][4];
#pragma unroll
  for (int nt = 0; nt < 4; ++nt) {
#pragma unroll
    for (int kk = 0; kk < 2; ++kk)
#pragma unroll
      for (int j = 0; j < 8; ++j)
        afrag[nt][kk][j] = (__bf16)Wo[(kk * 32 + kg * 8 + j) * 64 + nt * 16 + r];
#pragma unroll
    for (int j = 0; j < 4; ++j) {
      bias[nt][j] = bo[nt * 16 + kg * 4 + j];
      g1f[nt][j]  = g1[nt * 16 + kg * 4 + j];
      b1f[nt][j]  = b1[nt * 16 + kg * 4 + j];
    }
  }
  float invSv[8];
#pragma unroll
  for (int i = 0; i < 8; ++i) invSv[i] = 1.0f / S[i];

  const int ntile = N_NODES / 16;  // 3125
  const int nw = gridDim.x * 4;
  for (int t = blockIdx.x * 4 + wid; t < ntile; t += nw) {
    const int node = t * 16 + r;
    const float invc = 1.0f / (float)(rowptr[node + 1] - rowptr[node] + 1);
    bf16x8 bfrag[2];
#pragma unroll
    for (int kk = 0; kk < 2; ++kk) {
      float tmp[8];
      unpack8(*reinterpret_cast<const uint4*>(osum + (size_t)node * 64 + kk * 32 + kg * 8), tmp);
      const float sc = invSv[kk * 4 + kg] * invc;
      bf16x8 bf;
#pragma unroll
      for (int e = 0; e < 8; ++e) bf[e] = (__bf16)(tmp[e] * sc);
      bfrag[kk] = bf;
    }
    float tv[4][4];
    float sum = 0.f;
#pragma unroll
    for (int nt = 0; nt < 4; ++nt) {
      f32x4 acc = {bias[nt][0], bias[nt][1], bias[nt][2], bias[nt][3]};
      acc = __builtin_amdgcn_mfma_f32_16x16x32_bf16(afrag[nt][0], bfrag[0], acc, 0, 0, 0);
      acc = __builtin_amdgcn_mfma_f32_16x16x32_bf16(afrag[nt][1], bfrag[1], acc, 0, 0, 0);
      const float4 xv = *reinterpret_cast<const float4*>(x + (size_t)node * 64 + nt * 16 + kg * 4);
      tv[nt][0] = acc[0] + xv.x; tv[nt][1] = acc[1] + xv.y;
      tv[nt][2] = acc[2] + xv.z; tv[nt][3] = acc[3] + xv.w;
      sum += (tv[nt][0] + tv[nt][1]) + (tv[nt][2] + tv[nt][3]);
    }
    sum += __shfl_xor(sum, 16);
    sum += __shfl_xor(sum, 32);
    const float m = sum * (1.0f / 64.0f);
    float var = 0.f;
#pragma unroll
    for (int nt = 0; nt < 4; ++nt)
#pragma unroll
      for (int j = 0; j < 4; ++j) { const float d = tv[nt][j] - m; var = fmaf(d, d, var); }
    var += __shfl_xor(var, 16);
    var += __shfl_xor(var, 32);
    const float rinv = rsqrtf(var * (1.0f / 64.0f) + 1e-5f);
#pragma unroll
    for (int nt = 0; nt < 4; ++nt) {
      ushort4 pk;
      pk.x = f2bf((tv[nt][0] - m) * rinv * g1f[nt][0] + b1f[nt][0]);
      pk.y = f2bf((tv[nt][1] - m) * rinv * g1f[nt][1] + b1f[nt][1]);
      pk.z = f2bf((tv[nt][2] - m) * rinv * g1f[nt][2] + b1f[nt][2]);
      pk.w = f2bf((tv[nt][3] - m) * rinv * g1f[nt][3] + b1f[nt][3]);
      *reinterpret_cast<ushort4*>(h + (size_t)node * 64 + nt * 16 + kg * 4) = pk;
    }
  }
}

// ---------------- FFN1 via MFMA: f1 = gelu(h @ Wf1 + bf1) -> bf16 ----------------
__global__ __launch_bounds__(256) void k_ffn1_mfma(
    const ushort* __restrict__ h, const float* __restrict__ Wf1,
    const float* __restrict__ bf1, ushort* __restrict__ f1) {
  const int lane = threadIdx.x & 63;
  const int wid  = threadIdx.x >> 6;
  const int r  = lane & 15;
  const int kg = lane >> 4;

  bf16x8 afrag[8][2];
  float bias[8][4];
#pragma unroll
  for (int nt = 0; nt < 8; ++nt) {
#pragma unroll
    for (int kk = 0; kk < 2; ++kk)
#pragma unroll
      for (int j = 0; j < 8; ++j)
        afrag[nt][kk][j] = (__bf16)Wf1[(kk * 32 + kg * 8 + j) * 128 + nt * 16 + r];
#pragma unroll
    for (int j = 0; j < 4; ++j) bias[nt][j] = bf1[nt * 16 + kg * 4 + j];
  }

  const int ntile = N_NODES / 16;  // 3125
  const int nw = gridDim.x * 4;
  for (int t = blockIdx.x * 4 + wid; t < ntile; t += nw) {
    const int node = t * 16 + r;
    const bf16x8 bf0 = *reinterpret_cast<const bf16x8*>(h + (size_t)node * 64 + kg * 8);
    const bf16x8 bf1g = *reinterpret_cast<const bf16x8*>(h + (size_t)node * 64 + 32 + kg * 8);
#pragma unroll
    for (int nt = 0; nt < 8; ++nt) {
      f32x4 acc = {bias[nt][0], bias[nt][1], bias[nt][2], bias[nt][3]};
      acc = __builtin_amdgcn_mfma_f32_16x16x32_bf16(afrag[nt][0], bf0, acc, 0, 0, 0);
      acc = __builtin_amdgcn_mfma_f32_16x16x32_bf16(afrag[nt][1], bf1g, acc, 0, 0, 0);
      ushort4 pk;
      pk.x = f2bf(0.5f * acc[0] * (1.0f + erff(acc[0] * 0.7071067811865475f)));
      pk.y = f2bf(0.5f * acc[1] * (1.0f + erff(acc[1] * 0.7071067811865475f)));
      pk.z = f2bf(0.5f * acc[2] * (1.0f + erff(acc[2] * 0.7071067811865475f)));
      pk.w = f2bf(0.5f * acc[3] * (1.0f + erff(acc[3] * 0.7071067811865475f)));
      *reinterpret_cast<ushort4*>(f1 + (size_t)node * 128 + nt * 16 + kg * 4) = pk;
    }
  }
}

// ---------------- FFN2 via MFMA + residual + LN2 -> out (f32) ----------------
__global__ __launch_bounds__(256) void k_ffn2_mfma(
    const ushort* __restrict__ f1, const ushort* __restrict__ h,
    const float* __restrict__ Wf2, const float* __restrict__ bf2,
    const float* __restrict__ g2, const float* __restrict__ b2,
    float* __restrict__ out) {
  const int lane = threadIdx.x & 63;
  const int wid  = threadIdx.x >> 6;
  const int r  = lane & 15;
  const int kg = lane >> 4;

  bf16x8 afrag[4][4];
  float bias[4][4], g2f[4][4], b2f[4][4];
#pragma unroll
  for (int nt = 0; nt < 4; ++nt) {
#pragma unroll
    for (int kk = 0; kk < 4; ++kk)
#pragma unroll
      for (int j = 0; j < 8; ++j)
        afrag[nt][kk][j] = (__bf16)Wf2[(kk * 32 + kg * 8 + j) * 64 + nt * 16 + r];
#pragma unroll
    for (int j = 0; j < 4; ++j) {
      bias[nt][j] = bf2[nt * 16 + kg * 4 + j];
      g2f[nt][j]  = g2[nt * 16 + kg * 4 + j];
      b2f[nt][j]  = b2[nt * 16 + kg * 4 + j];
    }
  }

  const int ntile = N_NODES / 16;  // 3125
  const int nw = gridDim.x * 4;
  for (int t = blockIdx.x * 4 + wid; t < ntile; t += nw) {
    const int node = t * 16 + r;
    bf16x8 bfrag[4];
#pragma unroll
    for (int kk = 0; kk < 4; ++kk)
      bfrag[kk] = *reinterpret_cast<const bf16x8*>(f1 + (size_t)node * 128 + kk * 32 + kg * 8);
    float tv[4][4];
    float sum = 0.f;
#pragma unroll
    for (int nt = 0; nt < 4; ++nt) {
      f32x4 acc = {bias[nt][0], bias[nt][1], bias[nt][2], bias[nt][3]};
      acc = __builtin_amdgcn_mfma_f32_16x16x32_bf16(afrag[nt][0], bfrag[0], acc, 0, 0, 0);
      acc = __builtin_amdgcn_mfma_f32_16x16x32_bf16(afrag[nt][1], bfrag[1], acc, 0, 0, 0);
      acc = __builtin_amdgcn_mfma_f32_16x16x32_bf16(afrag[nt][2], bfrag[2], acc, 0, 0, 0);
      acc = __builtin_amdgcn_mfma_f32_16x16x32_bf16(afrag[nt][3], bfrag[3], acc, 0, 0, 0);
      const ushort4 hv = *reinterpret_cast<const ushort4*>(h + (size_t)node * 64 + nt * 16 + kg * 4);
      tv[nt][0] = acc[0] + bfu2f(hv.x); tv[nt][1] = acc[1] + bfu2f(hv.y);
      tv[nt][2] = acc[2] + bfu2f(hv.z); tv[nt][3] = acc[3] + bfu2f(hv.w);
      sum += (tv[nt][0] + tv[nt][1]) + (tv[nt][2] + tv[nt][3]);
    }
    sum += __shfl_xor(sum, 16);
    sum += __shfl_xor(sum, 32);
    const float m = sum * (1.0f / 64.0f);
    float var = 0.f;
#pragma unroll
    for (int nt = 0; nt < 4; ++nt)
#pragma unroll
      for (int j = 0; j < 4; ++j) { const float d = tv[nt][j] - m; var = fmaf(d, d, var); }
    var += __shfl_xor(var, 16);
    var += __shfl_xor(var, 32);
    const float rinv = rsqrtf(var * (1.0f / 64.0f) + 1e-5f);
#pragma unroll
    for (int nt = 0; nt < 4; ++nt) {
      float4 o;
      o.x = (tv[nt][0] - m) * rinv * g2f[nt][0] + b2f[nt][0];
      o.y = (tv[nt][1] - m) * rinv * g2f[nt][1] + b2f[nt][1];
      o.z = (tv[nt][2] - m) * rinv * g2f[nt][2] + b2f[nt][2];
      o.w = (tv[nt][3] - m) * rinv * g2f[nt][3] + b2f[nt][3];
      *reinterpret_cast<float4*>(out + (size_t)node * 64 + nt * 16 + kg * 4) = o;
    }
  }
}

extern "C" void kernel_launch(void* const* d_in, const int* in_sizes, int n_in,
                              void* d_out, int out_size, void* d_ws, size_t ws_size,
                              hipStream_t stream) {
  const float* x    = (const float*)d_in[0];
  const int*   ei   = (const int*)d_in[1];
  const int*   esrc = ei;
  const int*   edst = ei + N_EDGES;
  const float* ea   = (const float*)d_in[2];
  const float* Wq   = (const float*)d_in[3];
  const float* bq   = (const float*)d_in[4];
  const float* Wk   = (const float*)d_in[5];
  const float* bk   = (const float*)d_in[6];
  const float* Wv   = (const float*)d_in[7];
  const float* bv   = (const float*)d_in[8];
  const float* We   = (const float*)d_in[9];
  const float* be   = (const float*)d_in[10];
  const float* Wo   = (const float*)d_in[11];
  const float* bo   = (const float*)d_in[12];
  const float* g1   = (const float*)d_in[13];
  const float* b1   = (const float*)d_in[14];
  const float* g2   = (const float*)d_in[15];
  const float* b2   = (const float*)d_in[16];
  const float* Wf1  = (const float*)d_in[17];
  const float* bf1  = (const float*)d_in[18];
  const float* Wf2  = (const float*)d_in[19];
  const float* bf2  = (const float*)d_in[20];

  float* ws    = (float*)d_ws;
  ushort* q    = (ushort*)(ws + Q_OFF);
  unsigned char* kv8 = (unsigned char*)(ws + KV8_OFF);
  unsigned char* ee8 = (unsigned char*)(ws + EE_OFF);
  ushort* osum = (ushort*)(ws + OS_OFF);
  float* S     = ws + S_OFF;
  int*   rowptr = (int*)(ws + RP_OFF);
  int*   srcp   = (int*)(ws + SRCP_OFF);
  int*   pose   = (int*)(ws + POSE_OFF);
  int*   deg    = (int*)(ws + DEG_OFF);
  int*   woff   = (int*)(ws + WOFF_OFF);
  int*   bsum   = (int*)(ws + BSUM_OFF);
  ushort* h    = (ushort*)(ws + H_OFF);
  ushort* f1   = (ushort*)(ws + F1_OFF);
  float* out   = (float*)d_out;

  const dim3 B(256);
  const int edgeBlocks = (N_EDGES + 255) / 256;  // 3125

  k_qkv_mfma<<<dim3(256), B, 0, stream>>>(x, Wq, bq, Wk, bk, Wv, bv, q, kv8, deg, S);
  k_hist<<<dim3(edgeBlocks), B, 0, stream>>>(edst, deg);
  k_scan_a<<<dim3(NB), B, 0, stream>>>(deg, bsum);
  k_scan_c<<<dim3(NB), B, 0, stream>>>(deg, bsum, rowptr, woff);
  k_scatter<<<dim3(edgeBlocks), B, 0, stream>>>(esrc, edst, woff, srcp, pose);
  k_ee_mfma<<<dim3(1024), B, 0, stream>>>(pose, ea, We, be, ee8);
  k_gather<<<dim3(1024), B, 0, stream>>>(rowptr, srcp, ee8, q, kv8, be, osum, S);
  k_ln1_mfma<<<dim3(256), B, 0, stream>>>(osum, rowptr, S, x, Wo, bo, g1, b1, h);
  k_ffn1_mfma<<<dim3(256), B, 0, stream>>>(h, Wf1, bf1, f1);
  k_ffn2_mfma<<<dim3(256), B, 0, stream>>>(f1, h, Wf2, bf2, g2, b2, out);
}

// Round 16
// 265.448 us; speedup vs baseline: 1.4985x; 1.0098x over previous
//
#include <hip/hip_runtime.h>
#include <hip/hip_bf16.h>
#include <math.h>

#define N_NODES 50000
#define N_EDGES 800000
#define D 64
#define ED 32
#define NB 196   // node blocks = ceil(50000/256)

// ws layout (float-slot offsets). Total ~19.35M slots = 77.4 MB.
#define Q_OFF    0          // bf16 q (1.6M slots)
#define KV8_OFF  1600000    // fp8 k+v interleaved: 50k x 128 B = 1.6M slots
#define EE_OFF   3200000    // fp8 ee, dst-sorted: 800k x 64 B = 12.8M slots
#define OS_OFF   16000000   // bf16 osum: 1.6M slots
#define S_OFF    17600000   // 16
#define RP_OFF   17600016   // 50,001 (+1 pad)
#define SRCP_OFF 17650018   // 800k ints (src per sorted position)
#define POSE_OFF 18450018   // 800k ints (sorted position per orig edge)
#define DEG_OFF  19250018   // 50k ints
#define WOFF_OFF 19300018   // 50k ints
#define BSUM_OFF 19350018   // 256 ints

typedef __bf16 bf16x8 __attribute__((ext_vector_type(8)));
typedef float  f32x4  __attribute__((ext_vector_type(4)));

__device__ __forceinline__ ushort f2bf(float f) {
  uint u = __float_as_uint(f);
  uint r = (u + 0x7FFFu + ((u >> 16) & 1u)) >> 16;
  return (ushort)r;
}
__device__ __forceinline__ float bfu2f(ushort u) {
  return __uint_as_float(((uint)u) << 16);
}
__device__ __forceinline__ void unpack8(uint4 u, float (&f)[8]) {
  f[0] = __uint_as_float(u.x << 16); f[1] = __uint_as_float(u.x & 0xffff0000u);
  f[2] = __uint_as_float(u.y << 16); f[3] = __uint_as_float(u.y & 0xffff0000u);
  f[4] = __uint_as_float(u.z << 16); f[5] = __uint_as_float(u.z & 0xffff0000u);
  f[6] = __uint_as_float(u.w << 16); f[7] = __uint_as_float(u.w & 0xffff0000u);
}
__device__ __forceinline__ void unfp8(uint2 u, float (&f)[8]) {
  f[0] = __builtin_amdgcn_cvt_f32_fp8((int)u.x, 0);
  f[1] = __builtin_amdgcn_cvt_f32_fp8((int)u.x, 1);
  f[2] = __builtin_amdgcn_cvt_f32_fp8((int)u.x, 2);
  f[3] = __builtin_amdgcn_cvt_f32_fp8((int)u.x, 3);
  f[4] = __builtin_amdgcn_cvt_f32_fp8((int)u.y, 0);
  f[5] = __builtin_amdgcn_cvt_f32_fp8((int)u.y, 1);
  f[6] = __builtin_amdgcn_cvt_f32_fp8((int)u.y, 2);
  f[7] = __builtin_amdgcn_cvt_f32_fp8((int)u.y, 3);
}
__device__ __forceinline__ bf16x8 pack_bf8(float4 a, float4 b) {
  bf16x8 r;
  r[0] = (__bf16)a.x; r[1] = (__bf16)a.y; r[2] = (__bf16)a.z; r[3] = (__bf16)a.w;
  r[4] = (__bf16)b.x; r[5] = (__bf16)b.y; r[6] = (__bf16)b.z; r[7] = (__bf16)b.w;
  return r;
}
__device__ __forceinline__ uint pk_fp8(f32x4 acc) {
  uint rr = (uint)__builtin_amdgcn_cvt_pk_fp8_f32(acc[0], acc[1], 0, false);
  return (uint)__builtin_amdgcn_cvt_pk_fp8_f32(acc[2], acc[3], (int)rr, true);
}

// ---------------- QKV via MFMA: q -> bf16, k/v -> interleaved fp8 kv8 ----------------
__global__ __launch_bounds__(256) void k_qkv_mfma(
    const float* __restrict__ x,
    const float* __restrict__ Wq, const float* __restrict__ bq,
    const float* __restrict__ Wk, const float* __restrict__ bk,
    const float* __restrict__ Wv, const float* __restrict__ bv,
    ushort* __restrict__ q, unsigned char* __restrict__ kv8,
    int* __restrict__ deg, float* __restrict__ S) {
  const int tid0 = blockIdx.x * 256 + threadIdx.x;
  if (tid0 < N_NODES) deg[tid0] = 0;
  if (tid0 < 16) S[tid0] = 0.f;

  const int lane = threadIdx.x & 63;
  const int wid  = threadIdx.x >> 6;
  const int r  = lane & 15;
  const int kg = lane >> 4;
  const float* Ws[3] = {Wq, Wk, Wv};
  const float* bs[3] = {bq, bk, bv};

  bf16x8 afrag[3][4][2];
  float  bias[3][4][4];
#pragma unroll
  for (int m = 0; m < 3; ++m)
#pragma unroll
    for (int nt = 0; nt < 4; ++nt) {
#pragma unroll
      for (int kk = 0; kk < 2; ++kk)
#pragma unroll
        for (int j = 0; j < 8; ++j)
          afrag[m][nt][kk][j] = (__bf16)Ws[m][(kk * 32 + kg * 8 + j) * 64 + nt * 16 + r];
#pragma unroll
      for (int j = 0; j < 4; ++j) bias[m][nt][j] = bs[m][nt * 16 + kg * 4 + j];
    }

  const int ntile = N_NODES / 16;  // 3125
  const int nw = gridDim.x * 4;
  for (int t = blockIdx.x * 4 + wid; t < ntile; t += nw) {
    const int base = t * 16;
    const float4* xr = reinterpret_cast<const float4*>(x + (size_t)(base + r) * 64 + kg * 8);
    const bf16x8 xf0 = pack_bf8(xr[0], xr[1]);
    const bf16x8 xf1 = pack_bf8(xr[8], xr[9]);
#pragma unroll
    for (int m = 0; m < 3; ++m) {
#pragma unroll
      for (int nt = 0; nt < 4; ++nt) {
        f32x4 acc = {bias[m][nt][0], bias[m][nt][1], bias[m][nt][2], bias[m][nt][3]};
        acc = __builtin_amdgcn_mfma_f32_16x16x32_bf16(afrag[m][nt][0], xf0, acc, 0, 0, 0);
        acc = __builtin_amdgcn_mfma_f32_16x16x32_bf16(afrag[m][nt][1], xf1, acc, 0, 0, 0);
        if (m == 0) {
          ushort4 pk;
          pk.x = f2bf(acc[0]); pk.y = f2bf(acc[1]); pk.z = f2bf(acc[2]); pk.w = f2bf(acc[3]);
          *reinterpret_cast<ushort4*>(q + (size_t)(base + r) * 64 + nt * 16 + kg * 4) = pk;
        } else {
          const int sub = (m == 1) ? 0 : 8;
          const size_t off = (size_t)(base + r) * 128 +
                             (size_t)(nt * 2 + (kg >> 1)) * 16 + sub + (kg & 1) * 4;
          *reinterpret_cast<uint*>(kv8 + off) = pk_fp8(acc);
        }
      }
    }
  }
}

// ---------------- CSR build ----------------
__global__ __launch_bounds__(256) void k_hist(const int* __restrict__ edst,
                                              int* __restrict__ deg) {
  const int i = blockIdx.x * 256 + threadIdx.x;
  if (i < N_EDGES) atomicAdd(&deg[edst[i]], 1);
}

__global__ __launch_bounds__(256) void k_scan_a(const int* __restrict__ deg,
                                                int* __restrict__ bsum) {
  __shared__ int lds[256];
  const int i = blockIdx.x * 256 + threadIdx.x;
  lds[threadIdx.x] = (i < N_NODES) ? deg[i] : 0;
  __syncthreads();
  for (int s = 128; s > 0; s >>= 1) {
    if (threadIdx.x < s) lds[threadIdx.x] += lds[threadIdx.x + s];
    __syncthreads();
  }
  if (threadIdx.x == 0) bsum[blockIdx.x] = lds[0];
}

__global__ __launch_bounds__(256) void k_scan_c(const int* __restrict__ deg,
                                                const int* __restrict__ bsum,
                                                int* __restrict__ rowptr,
                                                int* __restrict__ woff) {
  __shared__ int lds[256];
  const int t = threadIdx.x;
  lds[t] = (t < blockIdx.x) ? bsum[t] : 0;   // blockIdx.x <= 195 < 256
  __syncthreads();
  for (int s = 128; s > 0; s >>= 1) {
    if (t < s) lds[t] += lds[t + s];
    __syncthreads();
  }
  const int base0 = lds[0];
  __syncthreads();
  const int i = blockIdx.x * 256 + t;
  const int d = (i < N_NODES) ? deg[i] : 0;
  lds[t] = d;
  __syncthreads();
  for (int off = 1; off < 256; off <<= 1) {
    const int val = (t >= off) ? lds[t - off] : 0;
    __syncthreads();
    lds[t] += val;
    __syncthreads();
  }
  const int ex = base0 + lds[t] - d;
  if (i < N_NODES) { rowptr[i] = ex; woff[i] = ex; }
  if (i == N_NODES - 1) rowptr[N_NODES] = ex + d;
}

__global__ __launch_bounds__(256) void k_scatter(const int* __restrict__ esrc,
                                                 const int* __restrict__ edst,
                                                 int* __restrict__ woff,
                                                 int* __restrict__ srcp,
                                                 int* __restrict__ pose) {
  const int i = blockIdx.x * 256 + threadIdx.x;
  if (i < N_EDGES) {
    const int pos = atomicAdd(&woff[edst[i]], 1);
    srcp[pos] = esrc[i];
    pose[i] = pos;
  }
}

// ---------------- ee GEMM via MFMA: sequential ea reads, scattered fp8 row writes ----------------
__global__ __launch_bounds__(256) void k_ee_mfma(
    const int* __restrict__ pose, const float* __restrict__ ea,
    const float* __restrict__ We, const float* __restrict__ be,
    unsigned char* __restrict__ ee8) {
  const int lane = threadIdx.x & 63;
  const int wid  = threadIdx.x >> 6;
  const int r  = lane & 15;
  const int kg = lane >> 4;

  bf16x8 afrag[4];
  float  bias[4][4];
#pragma unroll
  for (int nt = 0; nt < 4; ++nt) {
#pragma unroll
    for (int j = 0; j < 8; ++j)
      afrag[nt][j] = (__bf16)We[(kg * 8 + j) * 64 + nt * 16 + r];
#pragma unroll
    for (int j = 0; j < 4; ++j) bias[nt][j] = be[nt * 16 + kg * 4 + j];
  }

  const int ntile = N_EDGES / 16;  // 50000
  const int nw = gridDim.x * 4;
  for (int t = blockIdx.x * 4 + wid; t < ntile; t += nw) {
    const int base = t * 16;
    const int pos = pose[base + r];
    const float4* ar = reinterpret_cast<const float4*>(ea + (size_t)(base + r) * 32 + kg * 8);
    const bf16x8 bfrag = pack_bf8(ar[0], ar[1]);
#pragma unroll
    for (int nt = 0; nt < 4; ++nt) {
      f32x4 acc = {bias[nt][0], bias[nt][1], bias[nt][2], bias[nt][3]};
      acc = __builtin_amdgcn_mfma_f32_16x16x32_bf16(afrag[nt], bfrag, acc, 0, 0, 0);
      *reinterpret_cast<uint*>(ee8 + (size_t)pos * 64 + nt * 16 + kg * 4) = pk_fp8(acc);
    }
  }
}

// ---------------- gather: wave per node, lane=(edge-slot, head), ONE kv load/edge ----------------
__global__ __launch_bounds__(256) void k_gather(
    const int* __restrict__ rowptr, const int* __restrict__ srcp,
    const unsigned char* __restrict__ ee8,
    const ushort* __restrict__ qb, const unsigned char* __restrict__ kv8,
    const float* __restrict__ be,
    ushort* __restrict__ osum, float* __restrict__ S) {
  const int lane = threadIdx.x & 63;
  const int wid  = threadIdx.x >> 6;
  const int h = lane & 7, ei = lane >> 3;
  float bes[8];
#pragma unroll
  for (int i = 0; i < 8; ++i) bes[i] = be[h * 8 + i];
  float sacc = 0.f;
  const int nw = gridDim.x * 4;
  for (int n = blockIdx.x * 4 + wid; n < N_NODES; n += nw) {
    const int beg = rowptr[n], end = rowptr[n + 1];
    float qv[8];
    unpack8(*reinterpret_cast<const uint4*>(qb + (size_t)n * 64 + h * 8), qv);
    float macc[8];
#pragma unroll
    for (int i = 0; i < 8; ++i) macc[i] = 0.f;
    if (ei == 0) {  // self loop: ea=0 -> ee=be
      float kv[8], vv[8];
      const uint4 kvl = *reinterpret_cast<const uint4*>(kv8 + (size_t)n * 128 + h * 16);
      unfp8(make_uint2(kvl.x, kvl.y), kv);
      unfp8(make_uint2(kvl.z, kvl.w), vv);
      float sc = 0.f;
#pragma unroll
      for (int i = 0; i < 8; ++i) sc = fmaf(qv[i], kv[i] + bes[i], sc);
      const float w = __expf(sc * 0.3535533905932738f);
      sacc += w;
#pragma unroll
      for (int i = 0; i < 8; ++i) macc[i] = w * (vv[i] + bes[i]);
    }
    int p = beg + ei;
    int src = (p < end) ? srcp[p] : 0;
    for (; p < end; p += 8) {
      const int nsrc = (p + 8 < end) ? srcp[p + 8] : 0;
      float ev[8], kv[8], vv[8];
      unfp8(*reinterpret_cast<const uint2*>(ee8 + (size_t)p * 64 + h * 8), ev);
      const uint4 kvl = *reinterpret_cast<const uint4*>(kv8 + (size_t)src * 128 + h * 16);
      unfp8(make_uint2(kvl.x, kvl.y), kv);
      unfp8(make_uint2(kvl.z, kvl.w), vv);
      float sc = 0.f;
#pragma unroll
      for (int i = 0; i < 8; ++i) sc = fmaf(qv[i], kv[i] + ev[i], sc);
      const float w = __expf(sc * 0.3535533905932738f);
      sacc += w;
#pragma unroll
      for (int i = 0; i < 8; ++i) macc[i] = fmaf(w, vv[i] + ev[i], macc[i]);
      src = nsrc;
    }
#pragma unroll
    for (int i = 0; i < 8; ++i) {
      macc[i] += __shfl_xor(macc[i], 8);
      macc[i] += __shfl_xor(macc[i], 16);
      macc[i] += __shfl_xor(macc[i], 32);
    }
    if (ei == 0) {
      uint pk[4];
#pragma unroll
      for (int i = 0; i < 4; ++i)
        pk[i] = (uint)f2bf(macc[2 * i]) | ((uint)f2bf(macc[2 * i + 1]) << 16);
      *reinterpret_cast<uint4*>(osum + (size_t)n * 64 + h * 8) =
          make_uint4(pk[0], pk[1], pk[2], pk[3]);
    }
  }
  sacc += __shfl_xor(sacc, 8);
  sacc += __shfl_xor(sacc, 16);
  sacc += __shfl_xor(sacc, 32);
  if (ei == 0) atomicAdd(&S[h], sacc);
}

// ---------------- fused epilogue: LN1 -> FFN1(gelu) -> FFN2 -> LN2, one pass ----------------
// D->B layout conversion through wave-private padded LDS; h kept in registers for residual.
#define HST 72    // h LDS row stride (ushorts): 144 B -> 2-way bank conflicts only
#define FST 136   // f1 LDS row stride (ushorts): 272 B
__global__ __launch_bounds__(256, 1) void k_post(
    const ushort* __restrict__ osum, const int* __restrict__ rowptr,
    const float* __restrict__ S, const float* __restrict__ x,
    const float* __restrict__ Wo, const float* __restrict__ bo,
    const float* __restrict__ g1, const float* __restrict__ b1,
    const float* __restrict__ Wf1, const float* __restrict__ bf1,
    const float* __restrict__ Wf2, const float* __restrict__ bf2,
    const float* __restrict__ g2, const float* __restrict__ b2,
    float* __restrict__ out) {
  __shared__ ushort hls[4][16 * HST];
  __shared__ ushort f1ls[4][16 * FST];
  const int lane = threadIdx.x & 63;
  const int wid  = threadIdx.x >> 6;
  const int r  = lane & 15;
  const int kg = lane >> 4;
  ushort* hbase  = &hls[wid][0];
  ushort* f1base = &f1ls[wid][0];

  // resident weight fragments
  bf16x8 wo[4][2], w1[8][2], w2[4][4];
  float bof[4][4], g1f[4][4], b1f[4][4], b1v[8][4], bf2f[4][4], g2f[4][4], b2f[4][4];
#pragma unroll
  for (int nt = 0; nt < 4; ++nt) {
#pragma unroll
    for (int kk = 0; kk < 2; ++kk)
#pragma unroll
      for (int j = 0; j < 8; ++j)
        wo[nt][kk][j] = (__bf16)Wo[(kk * 32 + kg * 8 + j) * 64 + nt * 16 + r];
#pragma unroll
    for (int kk = 0; kk < 4; ++kk)
#pragma unroll
      for (int j = 0; j < 8; ++j)
        w2[nt][kk][j] = (__bf16)Wf2[(kk * 32 + kg * 8 + j) * 64 + nt * 16 + r];
#pragma unroll
    for (int j = 0; j < 4; ++j) {
      bof[nt][j] = bo[nt * 16 + kg * 4 + j];
      g1f[nt][j] = g1[nt * 16 + kg * 4 + j];
      b1f[nt][j] = b1[nt * 16 + kg * 4 + j];
      bf2f[nt][j] = bf2[nt * 16 + kg * 4 + j];
      g2f[nt][j] = g2[nt * 16 + kg * 4 + j];
      b2f[nt][j] = b2[nt * 16 + kg * 4 + j];
    }
  }
#pragma unroll
  for (int nt = 0; nt < 8; ++nt) {
#pragma unroll
    for (int kk = 0; kk < 2; ++kk)
#pragma unroll
      for (int j = 0; j < 8; ++j)
        w1[nt][kk][j] = (__bf16)Wf1[(kk * 32 + kg * 8 + j) * 128 + nt * 16 + r];
#pragma unroll
    for (int j = 0; j < 4; ++j) b1v[nt][j] = bf1[nt * 16 + kg * 4 + j];
  }
  float invSv[8];
#pragma unroll
  for (int i = 0; i < 8; ++i) invSv[i] = 1.0f / S[i];

  const int ntile = N_NODES / 16;  // 3125
  const int nw = gridDim.x * 4;
  for (int t = blockIdx.x * 4 + wid; t < ntile; t += nw) {
    const int node = t * 16 + r;
    // ---- phase A: ln1 ----
    const float invc = 1.0f / (float)(rowptr[node + 1] - rowptr[node] + 1);
    bf16x8 bfrag[2];
#pragma unroll
    for (int kk = 0; kk < 2; ++kk) {
      float tmp[8];
      unpack8(*reinterpret_cast<const uint4*>(osum + (size_t)node * 64 + kk * 32 + kg * 8), tmp);
      const float sc = invSv[kk * 4 + kg] * invc;
      bf16x8 bf;
#pragma unroll
      for (int e = 0; e < 8; ++e) bf[e] = (__bf16)(tmp[e] * sc);
      bfrag[kk] = bf;
    }
    float tv[4][4];
    float sum = 0.f;
#pragma unroll
    for (int nt = 0; nt < 4; ++nt) {
      f32x4 acc = {bof[nt][0], bof[nt][1], bof[nt][2], bof[nt][3]};
      acc = __builtin_amdgcn_mfma_f32_16x16x32_bf16(wo[nt][0], bfrag[0], acc, 0, 0, 0);
      acc = __builtin_amdgcn_mfma_f32_16x16x32_bf16(wo[nt][1], bfrag[1], acc, 0, 0, 0);
      const float4 xv = *reinterpret_cast<const float4*>(x + (size_t)node * 64 + nt * 16 + kg * 4);
      tv[nt][0] = acc[0] + xv.x; tv[nt][1] = acc[1] + xv.y;
      tv[nt][2] = acc[2] + xv.z; tv[nt][3] = acc[3] + xv.w;
      sum += (tv[nt][0] + tv[nt][1]) + (tv[nt][2] + tv[nt][3]);
    }
    sum += __shfl_xor(sum, 16);
    sum += __shfl_xor(sum, 32);
    const float m = sum * (1.0f / 64.0f);
    float var = 0.f;
#pragma unroll
    for (int nt = 0; nt < 4; ++nt)
#pragma unroll
      for (int j = 0; j < 4; ++j) { const float d = tv[nt][j] - m; var = fmaf(d, d, var); }
    var += __shfl_xor(var, 16);
    var += __shfl_xor(var, 32);
    const float rinv = rsqrtf(var * (1.0f / 64.0f) + 1e-5f);
    float hn[4][4];
#pragma unroll
    for (int nt = 0; nt < 4; ++nt) {
#pragma unroll
      for (int j = 0; j < 4; ++j)
        hn[nt][j] = (tv[nt][j] - m) * rinv * g1f[nt][j] + b1f[nt][j];
      ushort4 pk;
      pk.x = f2bf(hn[nt][0]); pk.y = f2bf(hn[nt][1]);
      pk.z = f2bf(hn[nt][2]); pk.w = f2bf(hn[nt][3]);
      *reinterpret_cast<ushort4*>(hbase + r * HST + nt * 16 + kg * 4) = pk;
    }
    // ---- phase B: ffn1 ----
    bf16x8 hB[2];
#pragma unroll
    for (int kk = 0; kk < 2; ++kk)
      hB[kk] = *reinterpret_cast<const bf16x8*>(hbase + r * HST + kk * 32 + kg * 8);
#pragma unroll
    for (int nt = 0; nt < 8; ++nt) {
      f32x4 acc = {b1v[nt][0], b1v[nt][1], b1v[nt][2], b1v[nt][3]};
      acc = __builtin_amdgcn_mfma_f32_16x16x32_bf16(w1[nt][0], hB[0], acc, 0, 0, 0);
      acc = __builtin_amdgcn_mfma_f32_16x16x32_bf16(w1[nt][1], hB[1], acc, 0, 0, 0);
      ushort4 pk;
      pk.x = f2bf(0.5f * acc[0] * (1.0f + erff(acc[0] * 0.7071067811865475f)));
      pk.y = f2bf(0.5f * acc[1] * (1.0f + erff(acc[1] * 0.7071067811865475f)));
      pk.z = f2bf(0.5f * acc[2] * (1.0f + erff(acc[2] * 0.7071067811865475f)));
      pk.w = f2bf(0.5f * acc[3] * (1.0f + erff(acc[3] * 0.7071067811865475f)));
      *reinterpret_cast<ushort4*>(f1base + r * FST + nt * 16 + kg * 4) = pk;
    }
    // ---- phase C: ffn2 + residual + ln2 ----
    bf16x8 fB[4];
#pragma unroll
    for (int kk = 0; kk < 4; ++kk)
      fB[kk] = *reinterpret_cast<const bf16x8*>(f1base + r * FST + kk * 32 + kg * 8);
    float sum2 = 0.f;
#pragma unroll
    for (int nt = 0; nt < 4; ++nt) {
      f32x4 acc = {bf2f[nt][0], bf2f[nt][1], bf2f[nt][2], bf2f[nt][3]};
      acc = __builtin_amdgcn_mfma_f32_16x16x32_bf16(w2[nt][0], fB[0], acc, 0, 0, 0);
      acc = __builtin_amdgcn_mfma_f32_16x16x32_bf16(w2[nt][1], fB[1], acc, 0, 0, 0);
      acc = __builtin_amdgcn_mfma_f32_16x16x32_bf16(w2[nt][2], fB[2], acc, 0, 0, 0);
      acc = __builtin_amdgcn_mfma_f32_16x16x32_bf16(w2[nt][3], fB[3], acc, 0, 0, 0);
      tv[nt][0] = acc[0] + hn[nt][0]; tv[nt][1] = acc[1] + hn[nt][1];
      tv[nt][2] = acc[2] + hn[nt][2]; tv[nt][3] = acc[3] + hn[nt][3];
      sum2 += (tv[nt][0] + tv[nt][1]) + (tv[nt][2] + tv[nt][3]);
    }
    sum2 += __shfl_xor(sum2, 16);
    sum2 += __shfl_xor(sum2, 32);
    const float m2 = sum2 * (1.0f / 64.0f);
    float var2 = 0.f;
#pragma unroll
    for (int nt = 0; nt < 4; ++nt)
#pragma unroll
      for (int j = 0; j < 4; ++j) { const float d = tv[nt][j] - m2; var2 = fmaf(d, d, var2); }
    var2 += __shfl_xor(var2, 16);
    var2 += __shfl_xor(var2, 32);
    const float rinv2 = rsqrtf(var2 * (1.0f / 64.0f) + 1e-5f);
#pragma unroll
    for (int nt = 0; nt < 4; ++nt) {
      float4 o;
      o.x = (tv[nt][0] - m2) * rinv2 * g2f[nt][0] + b2f[nt][0];
      o.y = (tv[nt][1] - m2) * rinv2 * g2f[nt][1] + b2f[nt][1];
      o.z = (tv[nt][2] - m2) * rinv2 * g2f[nt][2] + b2f[nt][2];
      o.w = (tv[nt][3] - m2) * rinv2 * g2f[nt][3] + b2f[nt][3];
      *reinterpret_cast<float4*>(out + (size_t)node * 64 + nt * 16 + kg * 4) = o;
    }
  }
}

extern "C" void kernel_launch(void* const* d_in, const int* in_sizes, int n_in,
                              void* d_out, int out_size, void* d_ws, size_t ws_size,
                              hipStream_t stream) {
  const float* x    = (const float*)d_in[0];
  const int*   ei   = (const int*)d_in[1];
  const int*   esrc = ei;
  const int*   edst = ei + N_EDGES;
  const float* ea   = (const float*)d_in[2];
  const float* Wq   = (const float*)d_in[3];
  const float* bq   = (const float*)d_in[4];
  const float* Wk   = (const float*)d_in[5];
  const float* bk   = (const float*)d_in[6];
  const float* Wv   = (const float*)d_in[7];
  const float* bv   = (const float*)d_in[8];
  const float* We   = (const float*)d_in[9];
  const float* be   = (const float*)d_in[10];
  const float* Wo   = (const float*)d_in[11];
  const float* bo   = (const float*)d_in[12];
  const float* g1   = (const float*)d_in[13];
  const float* b1   = (const float*)d_in[14];
  const float* g2   = (const float*)d_in[15];
  const float* b2   = (const float*)d_in[16];
  const float* Wf1  = (const float*)d_in[17];
  const float* bf1  = (const float*)d_in[18];
  const float* Wf2  = (const float*)d_in[19];
  const float* bf2  = (const float*)d_in[20];

  float* ws    = (float*)d_ws;
  ushort* q    = (ushort*)(ws + Q_OFF);
  unsigned char* kv8 = (unsigned char*)(ws + KV8_OFF);
  unsigned char* ee8 = (unsigned char*)(ws + EE_OFF);
  ushort* osum = (ushort*)(ws + OS_OFF);
  float* S     = ws + S_OFF;
  int*   rowptr = (int*)(ws + RP_OFF);
  int*   srcp   = (int*)(ws + SRCP_OFF);
  int*   pose   = (int*)(ws + POSE_OFF);
  int*   deg    = (int*)(ws + DEG_OFF);
  int*   woff   = (int*)(ws + WOFF_OFF);
  int*   bsum   = (int*)(ws + BSUM_OFF);
  float* out   = (float*)d_out;

  const dim3 B(256);
  const int edgeBlocks = (N_EDGES + 255) / 256;  // 3125

  k_qkv_mfma<<<dim3(256), B, 0, stream>>>(x, Wq, bq, Wk, bk, Wv, bv, q, kv8, deg, S);
  k_hist<<<dim3(edgeBlocks), B, 0, stream>>>(edst, deg);
  k_scan_a<<<dim3(NB), B, 0, stream>>>(deg, bsum);
  k_scan_c<<<dim3(NB), B, 0, stream>>>(deg, bsum, rowptr, woff);
  k_scatter<<<dim3(edgeBlocks), B, 0, stream>>>(esrc, edst, woff, srcp, pose);
  k_ee_mfma<<<dim3(1024), B, 0, stream>>>(pose, ea, We, be, ee8);
  k_gather<<<dim3(1024), B, 0, stream>>>(rowptr, srcp, ee8, q, kv8, be, osum, S);
  k_post<<<dim3(256), B, 0, stream>>>(osum, rowptr, S, x, Wo, bo, g1, b1,
                                      Wf1, bf1, Wf2, bf2, g2, b2, out);
}

// Round 18
// 262.872 us; speedup vs baseline: 1.5132x; 1.0098x over previous
//
#include <hip/hip_runtime.h>
#include <hip/hip_bf16.h>
#include <math.h>

#define N_NODES 50000
#define N_EDGES 800000
#define D 64
#define ED 32
#define NB 196   // node blocks = ceil(50000/256)

// ws layout (float-slot offsets). Total ~19.35M slots = 77.4 MB.
#define Q_OFF    0          // bf16 q (1.6M slots)
#define KV8_OFF  1600000    // fp8 k+v interleaved: 50k x 128 B = 1.6M slots
#define EE_OFF   3200000    // fp8 ee, dst-sorted: 800k x 64 B = 12.8M slots
#define OS_OFF   16000000   // bf16 osum: 1.6M slots
#define S_OFF    17600000   // 16
#define RP_OFF   17600016   // 50,001 (+1 pad)
#define SRCP_OFF 17650018   // 800k ints (src per sorted position)
#define POSE_OFF 18450018   // 800k ints (sorted position per orig edge)
#define DEG_OFF  19250018   // 50k ints
#define WOFF_OFF 19300018   // 50k ints
#define BSUM_OFF 19350018   // 256 ints

typedef __bf16 bf16x8 __attribute__((ext_vector_type(8)));
typedef float  f32x4  __attribute__((ext_vector_type(4)));

__device__ __forceinline__ ushort f2bf(float f) {
  uint u = __float_as_uint(f);
  uint r = (u + 0x7FFFu + ((u >> 16) & 1u)) >> 16;
  return (ushort)r;
}
__device__ __forceinline__ float bfu2f(ushort u) {
  return __uint_as_float(((uint)u) << 16);
}
__device__ __forceinline__ void unpack8(uint4 u, float (&f)[8]) {
  f[0] = __uint_as_float(u.x << 16); f[1] = __uint_as_float(u.x & 0xffff0000u);
  f[2] = __uint_as_float(u.y << 16); f[3] = __uint_as_float(u.y & 0xffff0000u);
  f[4] = __uint_as_float(u.z << 16); f[5] = __uint_as_float(u.z & 0xffff0000u);
  f[6] = __uint_as_float(u.w << 16); f[7] = __uint_as_float(u.w & 0xffff0000u);
}
__device__ __forceinline__ void unfp8(uint2 u, float (&f)[8]) {
  f[0] = __builtin_amdgcn_cvt_f32_fp8((int)u.x, 0);
  f[1] = __builtin_amdgcn_cvt_f32_fp8((int)u.x, 1);
  f[2] = __builtin_amdgcn_cvt_f32_fp8((int)u.x, 2);
  f[3] = __builtin_amdgcn_cvt_f32_fp8((int)u.x, 3);
  f[4] = __builtin_amdgcn_cvt_f32_fp8((int)u.y, 0);
  f[5] = __builtin_amdgcn_cvt_f32_fp8((int)u.y, 1);
  f[6] = __builtin_amdgcn_cvt_f32_fp8((int)u.y, 2);
  f[7] = __builtin_amdgcn_cvt_f32_fp8((int)u.y, 3);
}
__device__ __forceinline__ bf16x8 pack_bf8(float4 a, float4 b) {
  bf16x8 r;
  r[0] = (__bf16)a.x; r[1] = (__bf16)a.y; r[2] = (__bf16)a.z; r[3] = (__bf16)a.w;
  r[4] = (__bf16)b.x; r[5] = (__bf16)b.y; r[6] = (__bf16)b.z; r[7] = (__bf16)b.w;
  return r;
}
__device__ __forceinline__ uint pk_fp8(f32x4 acc) {
  uint rr = (uint)__builtin_amdgcn_cvt_pk_fp8_f32(acc[0], acc[1], 0, false);
  return (uint)__builtin_amdgcn_cvt_pk_fp8_f32(acc[2], acc[3], (int)rr, true);
}

// ---------------- QKV via MFMA: q -> bf16, k/v -> interleaved fp8 kv8 ----------------
__global__ __launch_bounds__(256) void k_qkv_mfma(
    const float* __restrict__ x,
    const float* __restrict__ Wq, const float* __restrict__ bq,
    const float* __restrict__ Wk, const float* __restrict__ bk,
    const float* __restrict__ Wv, const float* __restrict__ bv,
    ushort* __restrict__ q, unsigned char* __restrict__ kv8,
    int* __restrict__ deg, float* __restrict__ S) {
  const int tid0 = blockIdx.x * 256 + threadIdx.x;
  if (tid0 < N_NODES) deg[tid0] = 0;
  if (tid0 < 16) S[tid0] = 0.f;

  const int lane = threadIdx.x & 63;
  const int wid  = threadIdx.x >> 6;
  const int r  = lane & 15;
  const int kg = lane >> 4;
  const float* Ws[3] = {Wq, Wk, Wv};
  const float* bs[3] = {bq, bk, bv};

  bf16x8 afrag[3][4][2];
  float  bias[3][4][4];
#pragma unroll
  for (int m = 0; m < 3; ++m)
#pragma unroll
    for (int nt = 0; nt < 4; ++nt) {
#pragma unroll
      for (int kk = 0; kk < 2; ++kk)
#pragma unroll
        for (int j = 0; j < 8; ++j)
          afrag[m][nt][kk][j] = (__bf16)Ws[m][(kk * 32 + kg * 8 + j) * 64 + nt * 16 + r];
#pragma unroll
      for (int j = 0; j < 4; ++j) bias[m][nt][j] = bs[m][nt * 16 + kg * 4 + j];
    }

  const int ntile = N_NODES / 16;  // 3125
  const int nw = gridDim.x * 4;
  for (int t = blockIdx.x * 4 + wid; t < ntile; t += nw) {
    const int base = t * 16;
    const float4* xr = reinterpret_cast<const float4*>(x + (size_t)(base + r) * 64 + kg * 8);
    const bf16x8 xf0 = pack_bf8(xr[0], xr[1]);
    const bf16x8 xf1 = pack_bf8(xr[8], xr[9]);
#pragma unroll
    for (int m = 0; m < 3; ++m) {
#pragma unroll
      for (int nt = 0; nt < 4; ++nt) {
        f32x4 acc = {bias[m][nt][0], bias[m][nt][1], bias[m][nt][2], bias[m][nt][3]};
        acc = __builtin_amdgcn_mfma_f32_16x16x32_bf16(afrag[m][nt][0], xf0, acc, 0, 0, 0);
        acc = __builtin_amdgcn_mfma_f32_16x16x32_bf16(afrag[m][nt][1], xf1, acc, 0, 0, 0);
        if (m == 0) {
          ushort4 pk;
          pk.x = f2bf(acc[0]); pk.y = f2bf(acc[1]); pk.z = f2bf(acc[2]); pk.w = f2bf(acc[3]);
          *reinterpret_cast<ushort4*>(q + (size_t)(base + r) * 64 + nt * 16 + kg * 4) = pk;
        } else {
          const int sub = (m == 1) ? 0 : 8;
          const size_t off = (size_t)(base + r) * 128 +
                             (size_t)(nt * 2 + (kg >> 1)) * 16 + sub + (kg & 1) * 4;
          *reinterpret_cast<uint*>(kv8 + off) = pk_fp8(acc);
        }
      }
    }
  }
}

// ---------------- CSR build ----------------
__global__ __launch_bounds__(256) void k_hist(const int* __restrict__ edst,
                                              int* __restrict__ deg) {
  const int i = blockIdx.x * 256 + threadIdx.x;
  if (i < N_EDGES) atomicAdd(&deg[edst[i]], 1);
}

__global__ __launch_bounds__(256) void k_scan_a(const int* __restrict__ deg,
                                                int* __restrict__ bsum) {
  __shared__ int lds[256];
  const int i = blockIdx.x * 256 + threadIdx.x;
  lds[threadIdx.x] = (i < N_NODES) ? deg[i] : 0;
  __syncthreads();
  for (int s = 128; s > 0; s >>= 1) {
    if (threadIdx.x < s) lds[threadIdx.x] += lds[threadIdx.x + s];
    __syncthreads();
  }
  if (threadIdx.x == 0) bsum[blockIdx.x] = lds[0];
}

__global__ __launch_bounds__(256) void k_scan_c(const int* __restrict__ deg,
                                                const int* __restrict__ bsum,
                                                int* __restrict__ rowptr,
                                                int* __restrict__ woff) {
  __shared__ int lds[256];
  const int t = threadIdx.x;
  lds[t] = (t < blockIdx.x) ? bsum[t] : 0;   // blockIdx.x <= 195 < 256
  __syncthreads();
  for (int s = 128; s > 0; s >>= 1) {
    if (t < s) lds[t] += lds[t + s];
    __syncthreads();
  }
  const int base0 = lds[0];
  __syncthreads();
  const int i = blockIdx.x * 256 + t;
  const int d = (i < N_NODES) ? deg[i] : 0;
  lds[t] = d;
  __syncthreads();
  for (int off = 1; off < 256; off <<= 1) {
    const int val = (t >= off) ? lds[t - off] : 0;
    __syncthreads();
    lds[t] += val;
    __syncthreads();
  }
  const int ex = base0 + lds[t] - d;
  if (i < N_NODES) { rowptr[i] = ex; woff[i] = ex; }
  if (i == N_NODES - 1) rowptr[N_NODES] = ex + d;
}

__global__ __launch_bounds__(256) void k_scatter(const int* __restrict__ esrc,
                                                 const int* __restrict__ edst,
                                                 int* __restrict__ woff,
                                                 int* __restrict__ srcp,
                                                 int* __restrict__ pose) {
  const int i = blockIdx.x * 256 + threadIdx.x;
  if (i < N_EDGES) {
    const int pos = atomicAdd(&woff[edst[i]], 1);
    srcp[pos] = esrc[i];
    pose[i] = pos;
  }
}

// ---------------- ee GEMM via MFMA: sequential ea reads, scattered fp8 row writes ----------------
__global__ __launch_bounds__(256) void k_ee_mfma(
    const int* __restrict__ pose, const float* __restrict__ ea,
    const float* __restrict__ We, const float* __restrict__ be,
    unsigned char* __restrict__ ee8) {
  const int lane = threadIdx.x & 63;
  const int wid  = threadIdx.x >> 6;
  const int r  = lane & 15;
  const int kg = lane >> 4;

  bf16x8 afrag[4];
  float  bias[4][4];
#pragma unroll
  for (int nt = 0; nt < 4; ++nt) {
#pragma unroll
    for (int j = 0; j < 8; ++j)
      afrag[nt][j] = (__bf16)We[(kg * 8 + j) * 64 + nt * 16 + r];
#pragma unroll
    for (int j = 0; j < 4; ++j) bias[nt][j] = be[nt * 16 + kg * 4 + j];
  }

  const int ntile = N_EDGES / 16;  // 50000
  const int nw = gridDim.x * 4;
  for (int t = blockIdx.x * 4 + wid; t < ntile; t += nw) {
    const int base = t * 16;
    const int pos = pose[base + r];
    const float4* ar = reinterpret_cast<const float4*>(ea + (size_t)(base + r) * 32 + kg * 8);
    const bf16x8 bfrag = pack_bf8(ar[0], ar[1]);
#pragma unroll
    for (int nt = 0; nt < 4; ++nt) {
      f32x4 acc = {bias[nt][0], bias[nt][1], bias[nt][2], bias[nt][3]};
      acc = __builtin_amdgcn_mfma_f32_16x16x32_bf16(afrag[nt], bfrag, acc, 0, 0, 0);
      *reinterpret_cast<uint*>(ee8 + (size_t)pos * 64 + nt * 16 + kg * 4) = pk_fp8(acc);
    }
  }
}

// ---------------- gather: wave per node, lane=(edge-slot, head), ONE kv load/edge ----------------
__global__ __launch_bounds__(256) void k_gather(
    const int* __restrict__ rowptr, const int* __restrict__ srcp,
    const unsigned char* __restrict__ ee8,
    const ushort* __restrict__ qb, const unsigned char* __restrict__ kv8,
    const float* __restrict__ be,
    ushort* __restrict__ osum, float* __restrict__ S) {
  const int lane = threadIdx.x & 63;
  const int wid  = threadIdx.x >> 6;
  const int h = lane & 7, ei = lane >> 3;
  float bes[8];
#pragma unroll
  for (int i = 0; i < 8; ++i) bes[i] = be[h * 8 + i];
  float sacc = 0.f;
  const int nw = gridDim.x * 4;
  for (int n = blockIdx.x * 4 + wid; n < N_NODES; n += nw) {
    const int beg = rowptr[n], end = rowptr[n + 1];
    float qv[8];
    unpack8(*reinterpret_cast<const uint4*>(qb + (size_t)n * 64 + h * 8), qv);
    float macc[8];
#pragma unroll
    for (int i = 0; i < 8; ++i) macc[i] = 0.f;
    if (ei == 0) {  // self loop: ea=0 -> ee=be
      float kv[8], vv[8];
      const uint4 kvl = *reinterpret_cast<const uint4*>(kv8 + (size_t)n * 128 + h * 16);
      unfp8(make_uint2(kvl.x, kvl.y), kv);
      unfp8(make_uint2(kvl.z, kvl.w), vv);
      float sc = 0.f;
#pragma unroll
      for (int i = 0; i < 8; ++i) sc = fmaf(qv[i], kv[i] + bes[i], sc);
      const float w = __expf(sc * 0.3535533905932738f);
      sacc += w;
#pragma unroll
      for (int i = 0; i < 8; ++i) macc[i] = w * (vv[i] + bes[i]);
    }
    int p = beg + ei;
    int src = (p < end) ? srcp[p] : 0;
    for (; p < end; p += 8) {
      const int nsrc = (p + 8 < end) ? srcp[p + 8] : 0;
      float ev[8], kv[8], vv[8];
      unfp8(*reinterpret_cast<const uint2*>(ee8 + (size_t)p * 64 + h * 8), ev);
      const uint4 kvl = *reinterpret_cast<const uint4*>(kv8 + (size_t)src * 128 + h * 16);
      unfp8(make_uint2(kvl.x, kvl.y), kv);
      unfp8(make_uint2(kvl.z, kvl.w), vv);
      float sc = 0.f;
#pragma unroll
      for (int i = 0; i < 8; ++i) sc = fmaf(qv[i], kv[i] + ev[i], sc);
      const float w = __expf(sc * 0.3535533905932738f);
      sacc += w;
#pragma unroll
      for (int i = 0; i < 8; ++i) macc[i] = fmaf(w, vv[i] + ev[i], macc[i]);
      src = nsrc;
    }
#pragma unroll
    for (int i = 0; i < 8; ++i) {
      macc[i] += __shfl_xor(macc[i], 8);
      macc[i] += __shfl_xor(macc[i], 16);
      macc[i] += __shfl_xor(macc[i], 32);
    }
    if (ei == 0) {
      uint pk[4];
#pragma unroll
      for (int i = 0; i < 4; ++i)
        pk[i] = (uint)f2bf(macc[2 * i]) | ((uint)f2bf(macc[2 * i + 1]) << 16);
      *reinterpret_cast<uint4*>(osum + (size_t)n * 64 + h * 8) =
          make_uint4(pk[0], pk[1], pk[2], pk[3]);
    }
  }
  sacc += __shfl_xor(sacc, 8);
  sacc += __shfl_xor(sacc, 16);
  sacc += __shfl_xor(sacc, 32);
  if (ei == 0) atomicAdd(&S[h], sacc);
}

// ---------------- fused epilogue: LN1 -> FFN1(gelu) -> FFN2 -> LN2, one pass ----------------
#define HST 72    // h LDS row stride (ushorts): 144 B -> 2-way bank conflicts only
#define FST 136   // f1 LDS row stride (ushorts): 272 B
__global__ __launch_bounds__(256, 1) void k_post(
    const ushort* __restrict__ osum, const int* __restrict__ rowptr,
    const float* __restrict__ S, const float* __restrict__ x,
    const float* __restrict__ Wo, const float* __restrict__ bo,
    const float* __restrict__ g1, const float* __restrict__ b1,
    const float* __restrict__ Wf1, const float* __restrict__ bf1,
    const float* __restrict__ Wf2, const float* __restrict__ bf2,
    const float* __restrict__ g2, const float* __restrict__ b2,
    float* __restrict__ out) {
  __shared__ ushort hls[4][16 * HST];
  __shared__ ushort f1ls[4][16 * FST];
  const int lane = threadIdx.x & 63;
  const int wid  = threadIdx.x >> 6;
  const int r  = lane & 15;
  const int kg = lane >> 4;
  ushort* hbase  = &hls[wid][0];
  ushort* f1base = &f1ls[wid][0];

  bf16x8 wo[4][2], w1[8][2], w2[4][4];
  float bof[4][4], g1f[4][4], b1f[4][4], b1v[8][4], bf2f[4][4], g2f[4][4], b2f[4][4];
#pragma unroll
  for (int nt = 0; nt < 4; ++nt) {
#pragma unroll
    for (int kk = 0; kk < 2; ++kk)
#pragma unroll
      for (int j = 0; j < 8; ++j)
        wo[nt][kk][j] = (__bf16)Wo[(kk * 32 + kg * 8 + j) * 64 + nt * 16 + r];
#pragma unroll
    for (int kk = 0; kk < 4; ++kk)
#pragma unroll
      for (int j = 0; j < 8; ++j)
        w2[nt][kk][j] = (__bf16)Wf2[(kk * 32 + kg * 8 + j) * 64 + nt * 16 + r];
#pragma unroll
    for (int j = 0; j < 4; ++j) {
      bof[nt][j] = bo[nt * 16 + kg * 4 + j];
      g1f[nt][j] = g1[nt * 16 + kg * 4 + j];
      b1f[nt][j] = b1[nt * 16 + kg * 4 + j];
      bf2f[nt][j] = bf2[nt * 16 + kg * 4 + j];
      g2f[nt][j] = g2[nt * 16 + kg * 4 + j];
      b2f[nt][j] = b2[nt * 16 + kg * 4 + j];
    }
  }
#pragma unroll
  for (int nt = 0; nt < 8; ++nt) {
#pragma unroll
    for (int kk = 0; kk < 2; ++kk)
#pragma unroll
      for (int j = 0; j < 8; ++j)
        w1[nt][kk][j] = (__bf16)Wf1[(kk * 32 + kg * 8 + j) * 128 + nt * 16 + r];
#pragma unroll
    for (int j = 0; j < 4; ++j) b1v[nt][j] = bf1[nt * 16 + kg * 4 + j];
  }
  float invSv[8];
#pragma unroll
  for (int i = 0; i < 8; ++i) invSv[i] = 1.0f / S[i];

  const int ntile = N_NODES / 16;  // 3125
  const int nw = gridDim.x * 4;
  for (int t = blockIdx.x * 4 + wid; t < ntile; t += nw) {
    const int node = t * 16 + r;
    const float invc = 1.0f / (float)(rowptr[node + 1] - rowptr[node] + 1);
    bf16x8 bfrag[2];
#pragma unroll
    for (int kk = 0; kk < 2; ++kk) {
      float tmp[8];
      unpack8(*reinterpret_cast<const uint4*>(osum + (size_t)node * 64 + kk * 32 + kg * 8), tmp);
      const float sc = invSv[kk * 4 + kg] * invc;
      bf16x8 bf;
#pragma unroll
      for (int e = 0; e < 8; ++e) bf[e] = (__bf16)(tmp[e] * sc);
      bfrag[kk] = bf;
    }
    float tv[4][4];
    float sum = 0.f;
#pragma unroll
    for (int nt = 0; nt < 4; ++nt) {
      f32x4 acc = {bof[nt][0], bof[nt][1], bof[nt][2], bof[nt][3]};
      acc = __builtin_amdgcn_mfma_f32_16x16x32_bf16(wo[nt][0], bfrag[0], acc, 0, 0, 0);
      acc = __builtin_amdgcn_mfma_f32_16x16x32_bf16(wo[nt][1], bfrag[1], acc, 0, 0, 0);
      const float4 xv = *reinterpret_cast<const float4*>(x + (size_t)node * 64 + nt * 16 + kg * 4);
      tv[nt][0] = acc[0] + xv.x; tv[nt][1] = acc[1] + xv.y;
      tv[nt][2] = acc[2] + xv.z; tv[nt][3] = acc[3] + xv.w;
      sum += (tv[nt][0] + tv[nt][1]) + (tv[nt][2] + tv[nt][3]);
    }
    sum += __shfl_xor(sum, 16);
    sum += __shfl_xor(sum, 32);
    const float m = sum * (1.0f / 64.0f);
    float var = 0.f;
#pragma unroll
    for (int nt = 0; nt < 4; ++nt)
#pragma unroll
      for (int j = 0; j < 4; ++j) { const float d = tv[nt][j] - m; var = fmaf(d, d, var); }
    var += __shfl_xor(var, 16);
    var += __shfl_xor(var, 32);
    const float rinv = rsqrtf(var * (1.0f / 64.0f) + 1e-5f);
    float hn[4][4];
#pragma unroll
    for (int nt = 0; nt < 4; ++nt) {
#pragma unroll
      for (int j = 0; j < 4; ++j)
        hn[nt][j] = (tv[nt][j] - m) * rinv * g1f[nt][j] + b1f[nt][j];
      ushort4 pk;
      pk.x = f2bf(hn[nt][0]); pk.y = f2bf(hn[nt][1]);
      pk.z = f2bf(hn[nt][2]); pk.w = f2bf(hn[nt][3]);
      *reinterpret_cast<ushort4*>(hbase + r * HST + nt * 16 + kg * 4) = pk;
    }
    bf16x8 hB[2];
#pragma unroll
    for (int kk = 0; kk < 2; ++kk)
      hB[kk] = *reinterpret_cast<const bf16x8*>(hbase + r * HST + kk * 32 + kg * 8);
#pragma unroll
    for (int nt = 0; nt < 8; ++nt) {
      f32x4 acc = {b1v[nt][0], b1v[nt][1], b1v[nt][2], b1v[nt][3]};
      acc = __builtin_amdgcn_mfma_f32_16x16x32_bf16(w1[nt][0], hB[0], acc, 0, 0, 0);
      acc = __builtin_amdgcn_mfma_f32_16x16x32_bf16(w1[nt][1], hB[1], acc, 0, 0, 0);
      ushort4 pk;
      pk.x = f2bf(0.5f * acc[0] * (1.0f + erff(acc[0] * 0.7071067811865475f)));
      pk.y = f2bf(0.5f * acc[1] * (1.0f + erff(acc[1] * 0.7071067811865475f)));
      pk.z = f2bf(0.5f * acc[2] * (1.0f + erff(acc[2] * 0.7071067811865475f)));
      pk.w = f2bf(0.5f * acc[3] * (1.0f + erff(acc[3] * 0.7071067811865475f)));
      *reinterpret_cast<ushort4*>(f1base + r * FST + nt * 16 + kg * 4) = pk;
    }
    bf16x8 fB[4];
#pragma unroll
    for (int kk = 0; kk < 4; ++kk)
      fB[kk] = *reinterpret_cast<const bf16x8*>(f1base + r * FST + kk * 32 + kg * 8);
    float sum2 = 0.f;
#pragma unroll
    for (int nt = 0; nt < 4; ++nt) {
      f32x4 acc = {bf2f[nt][0], bf2f[nt][1], bf2f[nt][2], bf2f[nt][3]};
      acc = __builtin_amdgcn_mfma_f32_16x16x32_bf16(w2[nt][0], fB[0], acc, 0, 0, 0);
      acc = __builtin_amdgcn_mfma_f32_16x16x32_bf16(w2[nt][1], fB[1], acc, 0, 0, 0);
      acc = __builtin_amdgcn_mfma_f32_16x16x32_bf16(w2[nt][2], fB[2], acc, 0, 0, 0);
      acc = __builtin_amdgcn_mfma_f32_16x16x32_bf16(w2[nt][3], fB[3], acc, 0, 0, 0);
      tv[nt][0] = acc[0] + hn[nt][0]; tv[nt][1] = acc[1] + hn[nt][1];
      tv[nt][2] = acc[2] + hn[nt][2]; tv[nt][3] = acc[3] + hn[nt][3];
      sum2 += (tv[nt][0] + tv[nt][1]) + (tv[nt][2] + tv[nt][3]);
    }
    sum2 += __shfl_xor(sum2, 16);
    sum2 += __shfl_xor(sum2, 32);
    const float m2 = sum2 * (1.0f / 64.0f);
    float var2 = 0.f;
#pragma unroll
    for (int nt = 0; nt < 4; ++nt)
#pragma unroll
      for (int j = 0; j < 4; ++j) { const float d = tv[nt][j] - m2; var2 = fmaf(d, d, var2); }
    var2 += __shfl_xor(var2, 16);
    var2 += __shfl_xor(var2, 32);
    const float rinv2 = rsqrtf(var2 * (1.0f / 64.0f) + 1e-5f);
#pragma unroll
    for (int nt = 0; nt < 4; ++nt) {
      float4 o;
      o.x = (tv[nt][0] - m2) * rinv2 * g2f[nt][0] + b2f[nt][0];
      o.y = (tv[nt][1] - m2) * rinv2 * g2f[nt][1] + b2f[nt][1];
      o.z = (tv[nt][2] - m2) * rinv2 * g2f[nt][2] + b2f[nt][2];
      o.w = (tv[nt][3] - m2) * rinv2 * g2f[nt][3] + b2f[nt][3];
      *reinterpret_cast<float4*>(out + (size_t)node * 64 + nt * 16 + kg * 4) = o;
    }
  }
}

extern "C" void kernel_launch(void* const* d_in, const int* in_sizes, int n_in,
                              void* d_out, int out_size, void* d_ws, size_t ws_size,
                              hipStream_t stream) {
  const float* x    = (const float*)d_in[0];
  const int*   ei   = (const int*)d_in[1];
  const int*   esrc = ei;
  const int*   edst = ei + N_EDGES;
  const float* ea   = (const float*)d_in[2];
  const float* Wq   = (const float*)d_in[3];
  const float* bq   = (const float*)d_in[4];
  const float* Wk   = (const float*)d_in[5];
  const float* bk   = (const float*)d_in[6];
  const float* Wv   = (const float*)d_in[7];
  const float* bv   = (const float*)d_in[8];
  const float* We   = (const float*)d_in[9];
  const float* be   = (const float*)d_in[10];
  const float* Wo   = (const float*)d_in[11];
  const float* bo   = (const float*)d_in[12];
  const float* g1   = (const float*)d_in[13];
  const float* b1   = (const float*)d_in[14];
  const float* g2   = (const float*)d_in[15];
  const float* b2   = (const float*)d_in[16];
  const float* Wf1  = (const float*)d_in[17];
  const float* bf1  = (const float*)d_in[18];
  const float* Wf2  = (const float*)d_in[19];
  const float* bf2  = (const float*)d_in[20];

  float* ws    = (float*)d_ws;
  ushort* q    = (ushort*)(ws + Q_OFF);
  unsigned char* kv8 = (unsigned char*)(ws + KV8_OFF);
  unsigned char* ee8 = (unsigned char*)(ws + EE_OFF);
  ushort* osum = (ushort*)(ws + OS_OFF);
  float* S     = ws + S_OFF;
  int*   rowptr = (int*)(ws + RP_OFF);
  int*   srcp   = (int*)(ws + SRCP_OFF);
  int*   pose   = (int*)(ws + POSE_OFF);
  int*   deg    = (int*)(ws + DEG_OFF);
  int*   woff   = (int*)(ws + WOFF_OFF);
  int*   bsum   = (int*)(ws + BSUM_OFF);
  float* out   = (float*)d_out;

  const dim3 B(256);
  const int edgeBlocks = (N_EDGES + 255) / 256;  // 3125

  k_qkv_mfma<<<dim3(256), B, 0, stream>>>(x, Wq, bq, Wk, bk, Wv, bv, q, kv8, deg, S);
  k_hist<<<dim3(edgeBlocks), B, 0, stream>>>(edst, deg);
  k_scan_a<<<dim3(NB), B, 0, stream>>>(deg, bsum);
  k_scan_c<<<dim3(NB), B, 0, stream>>>(deg, bsum, rowptr, woff);
  k_scatter<<<dim3(edgeBlocks), B, 0, stream>>>(esrc, edst, woff, srcp, pose);
  k_ee_mfma<<<dim3(1024), B, 0, stream>>>(pose, ea, We, be, ee8);
  k_gather<<<dim3(1024), B, 0, stream>>>(rowptr, srcp, ee8, q, kv8, be, osum, S);
  k_post<<<dim3(256), B, 0, stream>>>(osum, rowptr, S, x, Wo, bo, g1, b1,
                                      Wf1, bf1, Wf2, bf2, g2, b2, out);
}